// Round 15
// baseline (660.157 us; speedup 1.0000x reference)
//
#include <hip/hip_runtime.h>
#include <cmath>

constexpr int B = 16, P = 2048, KNN = 5;
constexpr int BP = B * P;           // 32768
constexpr int E = BP * KNN;         // 163840
constexpr float EPS = 1e-5f;
constexpr int QC2 = 4;              // q-chunks for knn2 (occupancy: 2048 blocks)

// stats layout (floats): per stage [sum[C] | sumsq[C]]
constexpr int ST0 = 0;        // 64ch -> 128
constexpr int ST1 = 128;      // 64ch
constexpr int ST2 = 256;      // 64ch
constexpr int ST3 = 384;      // 128ch -> 256
constexpr int ST4 = 640;      // 1024ch -> 2048
constexpr int ST5 = 2688;     // 512ch -> 1024
constexpr int ST6 = 3712;     // 256ch -> 512
constexpr int ST_TOTAL = 4224;

typedef __attribute__((ext_vector_type(8))) short bf16x8;
typedef __attribute__((ext_vector_type(4))) float f32x4;

__device__ inline unsigned short f2bf(float x) {
    unsigned u = __float_as_uint(x);
    unsigned r = (u + 0x7FFFu + ((u >> 16) & 1u)) >> 16;
    return (unsigned short)r;
}
__device__ inline float bf2f(unsigned short h) {
    return __uint_as_float(((unsigned)h) << 16);
}
// split x into hi (bf16) and lo (bf16 of residual): x ~= hi + lo, err ~2^-18 rel
__device__ inline void split2bf(float x, unsigned short& h, unsigned short& l) {
    unsigned short hh = f2bf(x);
    h = hh;
    l = f2bf(x - bf2f(hh));
}

// branch-free sorted-5 insertion (ascending); constant indices -> stays in VGPRs.
__device__ inline void ins5(float d, int qi, float bd[KNN], int bi[KNN]) {
    bool c0 = d < bd[0], c1 = d < bd[1], c2 = d < bd[2], c3 = d < bd[3], c4 = d < bd[4];
    bd[4] = c3 ? bd[3] : (c4 ? d : bd[4]);  bi[4] = c3 ? bi[3] : (c4 ? qi : bi[4]);
    bd[3] = c2 ? bd[2] : (c3 ? d : bd[3]);  bi[3] = c2 ? bi[2] : (c3 ? qi : bi[3]);
    bd[2] = c1 ? bd[1] : (c2 ? d : bd[2]);  bi[2] = c1 ? bi[1] : (c2 ? qi : bi[2]);
    bd[1] = c0 ? bd[0] : (c1 ? d : bd[1]);  bi[1] = c0 ? bi[0] : (c1 ? qi : bi[1]);
    bd[0] = c0 ? d : bd[0];                 bi[0] = c0 ? qi : bi[0];
}
// insertion with lexicographic (d, qi) tie-break: keep lower q on exact fp tie
__device__ inline void ins5t(float d, int qi, float bd[KNN], int bi[KNN]) {
    bool c0 = (d < bd[0]) || (d == bd[0] && qi < bi[0]);
    bool c1 = (d < bd[1]) || (d == bd[1] && qi < bi[1]);
    bool c2 = (d < bd[2]) || (d == bd[2] && qi < bi[2]);
    bool c3 = (d < bd[3]) || (d == bd[3] && qi < bi[3]);
    bool c4 = (d < bd[4]) || (d == bd[4] && qi < bi[4]);
    bd[4] = c3 ? bd[3] : (c4 ? d : bd[4]);  bi[4] = c3 ? bi[3] : (c4 ? qi : bi[4]);
    bd[3] = c2 ? bd[2] : (c3 ? d : bd[3]);  bi[3] = c2 ? bi[2] : (c3 ? qi : bi[3]);
    bd[2] = c1 ? bd[1] : (c2 ? d : bd[2]);  bi[2] = c1 ? bi[1] : (c2 ? qi : bi[2]);
    bd[1] = c0 ? bd[0] : (c1 ? d : bd[1]);  bi[1] = c0 ? bi[0] : (c1 ? qi : bi[1]);
    bd[0] = c0 ? d : bd[0];                 bi[0] = c0 ? qi : bi[0];
}

// ---------------------------------------------------------------- init
__global__ void k_init(float* __restrict__ stats, float* __restrict__ pmax,
                       float* __restrict__ pmin) {
    int i = blockIdx.x * 256 + threadIdx.x;   // grid covers 16384
    if (i < ST_TOTAL) stats[i] = 0.f;
    if (i < B * 1024) { pmax[i] = 0.f; pmin[i] = INFINITY; }
}

// ---------------------------------------------------------------- deterministic partial reducer
__global__ __launch_bounds__(256) void k_redstat(const float* __restrict__ part,
        float* __restrict__ stats, int nblk) {
    __shared__ float r[256];
    int slot = blockIdx.x;
    float s = 0.f;
    for (int i = threadIdx.x; i < nblk; i += 256)
        s += part[(size_t)i * 128 + slot];
    r[threadIdx.x] = s; __syncthreads();
    for (int o = 128; o; o >>= 1) {
        if (threadIdx.x < o) r[threadIdx.x] += r[threadIdx.x + o];
        __syncthreads();
    }
    if (threadIdx.x == 0) stats[slot] = r[0];
}

// ---------------------------------------------------------------- weight pre-split: w[K][N] fp32 -> wt{h,l}[N][K] bf16
__global__ void k_wsplit(const float* __restrict__ w, unsigned short* __restrict__ th,
                         unsigned short* __restrict__ tl, int K, int N) {
    int i = blockIdx.x * 256 + threadIdx.x;
    if (i >= K * N) return;
    int k = i / N, n = i - k * N;          // read coalesced over n
    float f = w[i];
    unsigned short h = f2bf(f);
    th[(size_t)n * K + k] = h;
    tl[(size_t)n * K + k] = f2bf(f - bf2f(h));
}

// ---------------------------------------------------------------- BN-fold: wf[n][k] = scl[k]*w[k][n]; bias2 = bias + shf.w
// 64 blocks (n) x 64 threads (k); deterministic fixed LDS tree for bias2.
__global__ __launch_bounds__(64) void k_wfold(const float* __restrict__ stats,
        const float* __restrict__ g, const float* __restrict__ be,
        const float* __restrict__ w, const float* __restrict__ bias,
        unsigned short* __restrict__ wfh, unsigned short* __restrict__ wfl,
        float* __restrict__ bias2, float invN) {
    __shared__ float red[64];
    int n = blockIdx.x, k = threadIdx.x;
    float mu = stats[k] * invN;
    float var = stats[64 + k] * invN - mu * mu;
    float sc = g[k] * rsqrtf(var + EPS);
    float sh = be[k] - mu * sc;
    float wv = w[k * 64 + n];
    float wf = sc * wv;
    unsigned short h, l;
    split2bf(wf, h, l);
    wfh[n * 64 + k] = h; wfl[n * 64 + k] = l;
    red[k] = sh * wv; __syncthreads();
    for (int o = 32; o; o >>= 1) {
        if (k < o) red[k] += red[k + o];
        __syncthreads();
    }
    if (k == 0) bias2[n] = bias[n] + red[0];
}

// ---------------------------------------------------------------- ec2 weight prep: W0-W1 and W1, transposed bf16 hi/lo
// [xi, xj-xi] @ W  ==  xi @ (W0 - W1) + xj @ W1
__global__ void k_wprep2(const float* __restrict__ w,   // c2w [128][128]
        unsigned short* __restrict__ wdh, unsigned short* __restrict__ wdl,
        unsigned short* __restrict__ w1h, unsigned short* __restrict__ w1l) {
    int i = blockIdx.x * 256 + threadIdx.x;  // 64*128
    if (i >= 64 * 128) return;
    int k = i >> 7, n = i & 127;
    float w0 = w[k * 128 + n];
    float w1 = w[(64 + k) * 128 + n];
    float wd = w0 - w1;
    unsigned short h, l;
    split2bf(wd, h, l); wdh[n * 64 + k] = h; wdl[n * 64 + k] = l;
    split2bf(w1, h, l); w1h[n * 64 + k] = h; w1l[n * 64 + k] = l;
}

// ---------------------------------------------------------------- x pre-split (same layout): fp32 [N] -> bf16 hi/lo
__global__ void k_xsplit(const float* __restrict__ x, unsigned short* __restrict__ xh,
                         unsigned short* __restrict__ xl) {
    int i = blockIdx.x * 256 + threadIdx.x;
    float f = x[i];
    unsigned short h, l;
    split2bf(f, h, l);
    xh[i] = h; xl[i] = l;
}

// ---------------------------------------------------------------- kNN on pos (D=3)
__global__ __launch_bounds__(256) void k_knn1(const float* __restrict__ pos,
                                              int* __restrict__ idx1) {
    __shared__ float4 qt[2048];   // all q staged once (32 KB)
    int b = blockIdx.x >> 5;
    int p0 = (blockIdx.x & 31) << 6;
    const float* posb = pos + (size_t)b * P * 3;
#pragma unroll
    for (int t = 0; t < 8; ++t) {
        int q = (t << 8) + threadIdx.x;
        float qx = posb[q * 3 + 0], qy = posb[q * 3 + 1], qz = posb[q * 3 + 2];
        qt[q] = make_float4(qx, qy, qz, qx * qx + qy * qy + qz * qz);
    }
    __syncthreads();
    int pl = threadIdx.x >> 2, sub = threadIdx.x & 3;
    int p = p0 + pl;
    float4 me = qt[p];
    float x = me.x, y = me.y, z = me.z, sqp = me.w;
    float bd[KNN]; int bi[KNN];
#pragma unroll
    for (int i = 0; i < KNN; ++i) { bd[i] = INFINITY; bi[i] = 0; }
    for (int j0 = 0; j0 < 512; j0 += 8) {
        float4 v[8];
#pragma unroll
        for (int u = 0; u < 8; ++u) v[u] = qt[((j0 + u) << 2) | sub];
#pragma unroll
        for (int u = 0; u < 8; ++u) {
            float dot = x * v[u].x + y * v[u].y + z * v[u].z;
            float d2 = sqp + v[u].w - 2.f * dot;
            if (d2 < bd[KNN - 1]) ins5(d2, ((j0 + u) << 2) | sub, bd, bi);
        }
    }
    // butterfly merge across the 4 subs; snapshot-then-insert
#pragma unroll
    for (int w = 1; w <= 2; w <<= 1) {
        float od[KNN]; int oi[KNN];
#pragma unroll
        for (int i = 0; i < KNN; ++i) {
            od[i] = __shfl_xor(bd[i], w, 64);
            oi[i] = __shfl_xor(bi[i], w, 64);
        }
#pragma unroll
        for (int i = 0; i < KNN; ++i) ins5t(od[i], oi[i], bd, bi);
    }
    if (sub == 0) {
        size_t o = ((size_t)b * P + p) * KNN;
#pragma unroll
        for (int i = 0; i < KNN; ++i) idx1[o + i] = bi[i];
    }
}

// ---------------------------------------------------------------- edgeconv1 layer0: e[6] @ w[6,64]; bf16 hi/lo out + partials
__global__ __launch_bounds__(256) void k_ec1_l0(const float* __restrict__ pos,
        const int* __restrict__ idx1, const float* __restrict__ w,
        const float* __restrict__ bias, unsigned short* __restrict__ zh,
        unsigned short* __restrict__ zl, float* __restrict__ part) {
    __shared__ float elds[256][6];
    __shared__ float red[256];
    int tid = threadIdx.x;
    int base = blockIdx.x * 256;
    {
        int e = base + tid;
        int bp = e / KNN;
        int bb = bp >> 11;
        int q = idx1[e];
        const float* pi = pos + (size_t)bp * 3;
        const float* pj = pos + ((size_t)(bb << 11) + q) * 3;
        float x0 = pi[0], x1v = pi[1], x2v = pi[2];
        elds[tid][0] = x0; elds[tid][1] = x1v; elds[tid][2] = x2v;
        elds[tid][3] = pj[0] - x0; elds[tid][4] = pj[1] - x1v; elds[tid][5] = pj[2] - x2v;
    }
    int c = tid & 63, lane = tid >> 6;
    float wr[6];
#pragma unroll
    for (int d = 0; d < 6; ++d) wr[d] = w[d * 64 + c];
    float bc = bias[c];
    __syncthreads();
    float s1 = 0.f, s2 = 0.f;
    for (int i = 0; i < 64; ++i) {
        int e = lane + (i << 2);
        float acc = bc;
#pragma unroll
        for (int d = 0; d < 6; ++d) acc = fmaf(elds[e][d], wr[d], acc);
        acc = fmaxf(acc, 0.f);
        unsigned short h, l;
        split2bf(acc, h, l);
        zh[(size_t)(base + e) * 64 + c] = h;
        zl[(size_t)(base + e) * 64 + c] = l;
        s1 += acc; s2 = fmaf(acc, acc, s2);
    }
    red[tid] = s1; __syncthreads();
    if (tid < 64) part[(size_t)blockIdx.x * 128 + tid] =
        red[tid] + red[tid + 64] + red[tid + 128] + red[tid + 192];
    __syncthreads();
    red[tid] = s2; __syncthreads();
    if (tid < 64) part[(size_t)blockIdx.x * 128 + 64 + tid] =
        red[tid] + red[tid + 64] + red[tid + 128] + red[tid + 192];
}

// ---------------------------------------------------------------- 64->64 layer (BN folded into weights; direct-frag MFMA)
// zout = relu(zin @ wf + bias2); A from zin bf16 hi/lo (row-major == MFMA A
// layout), B from folded wf. Writes bf16 hi/lo + per-block stat partials.
__global__ __launch_bounds__(128) void k_lin64m(
        const unsigned short* __restrict__ zinh, const unsigned short* __restrict__ zinl,
        const unsigned short* __restrict__ wfh, const unsigned short* __restrict__ wfl,
        const float* __restrict__ bias2, unsigned short* __restrict__ zouth,
        unsigned short* __restrict__ zoutl, float* __restrict__ part) {
    __shared__ float red[2 * 64 * 2];
    int tid = threadIdx.x;
    int wv = tid >> 6, lane = tid & 63;
    int l15 = lane & 15, quad = lane >> 4;
    int row0 = blockIdx.x * 128 + wv * 64;
    f32x4 acc[4][4];
#pragma unroll
    for (int i = 0; i < 4; ++i)
#pragma unroll
        for (int j = 0; j < 4; ++j) acc[i][j] = (f32x4)0.f;

#pragma unroll
    for (int kc = 0; kc < 2; ++kc) {
        bf16x8 afh[4], afl[4], bfh[4], bfl[4];
#pragma unroll
        for (int i = 0; i < 4; ++i) {
            size_t o = (size_t)(row0 + i * 16 + l15) * 64 + kc * 32 + quad * 8;
            afh[i] = *(const bf16x8*)&zinh[o];
            afl[i] = *(const bf16x8*)&zinl[o];
        }
#pragma unroll
        for (int j = 0; j < 4; ++j) {
            size_t wo = (size_t)(j * 16 + l15) * 64 + kc * 32 + quad * 8;
            bfh[j] = *(const bf16x8*)&wfh[wo];
            bfl[j] = *(const bf16x8*)&wfl[wo];
        }
#pragma unroll
        for (int i = 0; i < 4; ++i)
#pragma unroll
            for (int j = 0; j < 4; ++j) {
                acc[i][j] = __builtin_amdgcn_mfma_f32_16x16x32_bf16(afh[i], bfh[j], acc[i][j], 0, 0, 0);
                acc[i][j] = __builtin_amdgcn_mfma_f32_16x16x32_bf16(afh[i], bfl[j], acc[i][j], 0, 0, 0);
                acc[i][j] = __builtin_amdgcn_mfma_f32_16x16x32_bf16(afl[i], bfh[j], acc[i][j], 0, 0, 0);
            }
    }
    // epilogue: bias + ReLU, bf16 split store, per-col stats
#pragma unroll
    for (int j = 0; j < 4; ++j) {
        int colL = j * 16 + l15;
        float bl = bias2[colL];
        float s1 = 0.f, s2 = 0.f;
#pragma unroll
        for (int i = 0; i < 4; ++i) {
            int row = row0 + i * 16 + quad * 4;
#pragma unroll
            for (int r = 0; r < 4; ++r) {
                float v = fmaxf(acc[i][j][r] + bl, 0.f);
                unsigned short h, l;
                split2bf(v, h, l);
                zouth[(size_t)(row + r) * 64 + colL] = h;
                zoutl[(size_t)(row + r) * 64 + colL] = l;
                s1 += v; s2 = fmaf(v, v, s2);
            }
        }
        s1 += __shfl_xor(s1, 16, 64); s1 += __shfl_xor(s1, 32, 64);
        s2 += __shfl_xor(s2, 16, 64); s2 += __shfl_xor(s2, 32, 64);
        if (quad == 0) {
            red[(wv * 64 + colL) * 2 + 0] = s1;
            red[(wv * 64 + colL) * 2 + 1] = s2;
        }
    }
    __syncthreads();
    if (tid < 64) {
        part[(size_t)blockIdx.x * 128 + tid] =
            red[tid * 2] + red[(64 + tid) * 2];
        part[(size_t)blockIdx.x * 128 + 64 + tid] =
            red[tid * 2 + 1] + red[(64 + tid) * 2 + 1];
    }
}

// ---------------------------------------------------------------- ec1 finalize: BN + max over k -> x1, sq norms (bf16 hi/lo in)
__global__ __launch_bounds__(256) void k_ec1_fin(const unsigned short* __restrict__ z2h,
        const unsigned short* __restrict__ z2l,
        const float* __restrict__ statsIn, const float* __restrict__ g,
        const float* __restrict__ be, float* __restrict__ x1,
        float* __restrict__ sq2) {
    int tid = threadIdx.x;
    int o = blockIdx.x * 256 + tid;
    int c = o & 63; int bp = o >> 6;
    float mu = statsIn[c] * (1.f / E);
    float var = statsIn[64 + c] * (1.f / E) - mu * mu;
    float sc = g[c] * rsqrtf(var + EPS);
    float sh = be[c] - mu * sc;
    float m = -INFINITY;
#pragma unroll
    for (int j = 0; j < KNN; ++j) {
        size_t zo = ((size_t)bp * KNN + j) * 64 + c;
        float v = bf2f(z2h[zo]) + bf2f(z2l[zo]);
        m = fmaxf(m, fmaf(v, sc, sh));
    }
    x1[o] = m;
    float ss = m * m;
#pragma unroll
    for (int off = 32; off; off >>= 1) ss += __shfl_down(ss, off, 64);
    if (c == 0) sq2[bp] = ss;
}

// ---------------------------------------------------------------- kNN2 partial (split-bf16 MFMA Gram + top-5 per q-chunk)
__global__ __launch_bounds__(128, 1) void k_knn2(const unsigned short* __restrict__ x1h,
        const unsigned short* __restrict__ x1l, const float* __restrict__ sq2,
        float* __restrict__ cd, int* __restrict__ ci) {
    __shared__ float S[2][32 * 129];   // per-wave key tile, stride 129 (bank rotate)
    int tid = threadIdx.x;
    int wv = tid >> 6, lane = tid & 63;
    int l15 = lane & 15, quad = lane >> 4;
    int qc = blockIdx.x & (QC2 - 1);
    int pt = blockIdx.x >> 2;                 // 16*32 ptiles of 64 rows
    int b = pt >> 5;
    int pw = ((pt & 31) << 6) + wv * 32;      // wave p base within batch
    const size_t xbase = (size_t)b * P * 64;
    float* Sw = &S[wv][0];

    // A fragments (rows pw..pw+31), kept for the whole kernel
    bf16x8 ah[2][2], al[2][2];
#pragma unroll
    for (int i = 0; i < 2; ++i)
#pragma unroll
        for (int kc = 0; kc < 2; ++kc) {
            size_t o = xbase + (size_t)(pw + i * 16 + l15) * 64 + kc * 32 + quad * 8;
            ah[i][kc] = *(const bf16x8*)&x1h[o];
            al[i][kc] = *(const bf16x8*)&x1l[o];
        }

    int half = lane >> 5;      // 0/1: which q-half this lane scans
    int pidx = lane & 31;      // which p row this lane scans
    float bd[KNN]; int bi[KNN];
#pragma unroll
    for (int i = 0; i < KNN; ++i) { bd[i] = INFINITY; bi[i] = 0; }

    int qlo = qc << 9;         // 512-q chunk
    for (int t = 0; t < 4; ++t) {
        int q0 = qlo + (t << 7);
        float qsv[8];
#pragma unroll
        for (int j = 0; j < 8; ++j) qsv[j] = sq2[b * P + q0 + j * 16 + l15];
        f32x4 acc[2][8];
#pragma unroll
        for (int i = 0; i < 2; ++i)
#pragma unroll
            for (int j = 0; j < 8; ++j) acc[i][j] = (f32x4)0.f;
#pragma unroll
        for (int kc = 0; kc < 2; ++kc) {
            bf16x8 bh[8], bl[8];
#pragma unroll
            for (int j = 0; j < 8; ++j) {
                size_t o = xbase + (size_t)(q0 + j * 16 + l15) * 64 + kc * 32 + quad * 8;
                bh[j] = *(const bf16x8*)&x1h[o];
                bl[j] = *(const bf16x8*)&x1l[o];
            }
#pragma unroll
            for (int i = 0; i < 2; ++i)
#pragma unroll
                for (int j = 0; j < 8; ++j) {
                    acc[i][j] = __builtin_amdgcn_mfma_f32_16x16x32_bf16(ah[i][kc], bh[j], acc[i][j], 0, 0, 0);
                    acc[i][j] = __builtin_amdgcn_mfma_f32_16x16x32_bf16(ah[i][kc], bl[j], acc[i][j], 0, 0, 0);
                    acc[i][j] = __builtin_amdgcn_mfma_f32_16x16x32_bf16(al[i][kc], bh[j], acc[i][j], 0, 0, 0);
                }
        }
        // keys to LDS: S[p_local][q_local] = sq_q - 2*dot (sq_p dropped: row-constant)
#pragma unroll
        for (int i = 0; i < 2; ++i)
#pragma unroll
            for (int j = 0; j < 8; ++j)
#pragma unroll
                for (int r = 0; r < 4; ++r) {
                    int pl = i * 16 + quad * 4 + r;
                    Sw[pl * 129 + j * 16 + l15] = fmaf(acc[i][j][r], -2.f, qsv[j]);
                }
        // scan own rows (same wave wrote them; DS in-order -> no barrier)
        const float* row = Sw + pidx * 129 + half * 64;
        int qb = q0 + half * 64;
        for (int jj = 0; jj < 64; jj += 4) {
            float k0 = row[jj + 0], k1 = row[jj + 1], k2 = row[jj + 2], k3 = row[jj + 3];
            if (k0 < bd[4]) ins5(k0, qb + jj + 0, bd, bi);
            if (k1 < bd[4]) ins5(k1, qb + jj + 1, bd, bi);
            if (k2 < bd[4]) ins5(k2, qb + jj + 2, bd, bi);
            if (k3 < bd[4]) ins5(k3, qb + jj + 3, bd, bi);
        }
    }
    // merge the two half-lanes (one-directional: half==1's list stays immutable)
#pragma unroll
    for (int i = 0; i < KNN; ++i) {
        float od = __shfl_xor(bd[i], 32, 64);
        int oi = __shfl_xor(bi[i], 32, 64);
        if (half == 0) ins5t(od, oi, bd, bi);
    }
    if (half == 0) {
        size_t o = (((size_t)b * P + pw + pidx) * QC2 + qc) * KNN;
#pragma unroll
        for (int i = 0; i < KNN; ++i) { cd[o + i] = bd[i]; ci[o + i] = bi[i]; }
    }
}

// ---------------------------------------------------------------- kNN2 merge (QC2 sorted chunks of 5 -> 5)
__global__ __launch_bounds__(256) void k_knn2m(const float* __restrict__ cd,
        const int* __restrict__ ci, int* __restrict__ idx2) {
    int bp = blockIdx.x * 256 + threadIdx.x;
    float bd[KNN]; int bi[KNN];
#pragma unroll
    for (int i = 0; i < KNN; ++i) { bd[i] = INFINITY; bi[i] = 0; }
    size_t o = (size_t)bp * QC2 * KNN;
    for (int t = 0; t < QC2 * KNN; ++t) {
        float d2 = cd[o + t]; int qi = ci[o + t];
        if (d2 < bd[KNN - 1]) ins5(d2, qi, bd, bi);
    }
#pragma unroll
    for (int i = 0; i < KNN; ++i) idx2[bp * KNN + i] = bi[i];
}

// ---------------------------------------------------------------- edgeconv2 (direct-fragment split-bf16 MFMA)
__global__ __launch_bounds__(256) void k_ec2m(
        const unsigned short* __restrict__ x1h, const unsigned short* __restrict__ x1l,
        const int* __restrict__ idx2,
        const unsigned short* __restrict__ wdh, const unsigned short* __restrict__ wdl,
        const unsigned short* __restrict__ w1h, const unsigned short* __restrict__ w1l,
        const float* __restrict__ bias, float* __restrict__ zout,
        float* __restrict__ stats) {
    __shared__ float red[2 * 128 * 2];
    int tid = threadIdx.x;
    int base = blockIdx.x * 128;            // first edge
    int bb = base / (P * KNN);              // batch (blocks never straddle: 10240%128==0)
    int wv = tid >> 6, lane = tid & 63;
    int wm = wv >> 1, wn = wv & 1;
    int l15 = lane & 15, quad = lane >> 4;
    // per-lane A rows for this wave's 4 row-tiles
    int rI[4], rJ[4];
#pragma unroll
    for (int i = 0; i < 4; ++i) {
        int e = base + wm * 64 + i * 16 + l15;
        rI[i] = e / KNN;
        rJ[i] = (bb << 11) + idx2[e];
    }
    f32x4 acc[4][4];
#pragma unroll
    for (int i = 0; i < 4; ++i)
#pragma unroll
        for (int j = 0; j < 4; ++j) acc[i][j] = (f32x4)0.f;

#pragma unroll
    for (int s = 0; s < 2; ++s) {
        const unsigned short* bh_ = s ? w1h : wdh;
        const unsigned short* bl_ = s ? w1l : wdl;
#pragma unroll
        for (int kc = 0; kc < 2; ++kc) {
            bf16x8 afh[4], afl[4], bfh[4], bfl[4];
#pragma unroll
            for (int i = 0; i < 4; ++i) {
                int row = s ? rJ[i] : rI[i];
                size_t o = (size_t)row * 64 + kc * 32 + quad * 8;
                afh[i] = *(const bf16x8*)&x1h[o];
                afl[i] = *(const bf16x8*)&x1l[o];
            }
#pragma unroll
            for (int j = 0; j < 4; ++j) {
                size_t wo = (size_t)(wn * 64 + j * 16 + l15) * 64 + kc * 32 + quad * 8;
                bfh[j] = *(const bf16x8*)&bh_[wo];
                bfl[j] = *(const bf16x8*)&bl_[wo];
            }
#pragma unroll
            for (int i = 0; i < 4; ++i)
#pragma unroll
                for (int j = 0; j < 4; ++j) {
                    acc[i][j] = __builtin_amdgcn_mfma_f32_16x16x32_bf16(afh[i], bfh[j], acc[i][j], 0, 0, 0);
                    acc[i][j] = __builtin_amdgcn_mfma_f32_16x16x32_bf16(afh[i], bfl[j], acc[i][j], 0, 0, 0);
                    acc[i][j] = __builtin_amdgcn_mfma_f32_16x16x32_bf16(afl[i], bfh[j], acc[i][j], 0, 0, 0);
                }
        }
    }
    // epilogue: bias + ReLU, write z, per-col stats
#pragma unroll
    for (int j = 0; j < 4; ++j) {
        int colL = wn * 64 + j * 16 + l15;
        float bl = bias[colL];
        float s1 = 0.f, s2 = 0.f;
#pragma unroll
        for (int i = 0; i < 4; ++i) {
            int row = wm * 64 + i * 16 + quad * 4;
#pragma unroll
            for (int r = 0; r < 4; ++r) {
                float v = fmaxf(acc[i][j][r] + bl, 0.f);
                zout[(size_t)(base + row + r) * 128 + colL] = v;
                s1 += v; s2 = fmaf(v, v, s2);
            }
        }
        s1 += __shfl_xor(s1, 16, 64); s1 += __shfl_xor(s1, 32, 64);
        s2 += __shfl_xor(s2, 16, 64); s2 += __shfl_xor(s2, 32, 64);
        if (quad == 0) {
            red[(wm * 128 + colL) * 2 + 0] = s1;
            red[(wm * 128 + colL) * 2 + 1] = s2;
        }
    }
    __syncthreads();
    if (tid < 128) {
        atomicAdd(&stats[tid], red[tid * 2] + red[(128 + tid) * 2]);
        atomicAdd(&stats[128 + tid], red[tid * 2 + 1] + red[(128 + tid) * 2 + 1]);
    }
}

// ---------------------------------------------------------------- ec2 finalize: BN + max over k -> x2
__global__ __launch_bounds__(256) void k_ec2_fin(const float* __restrict__ z3,
        const float* __restrict__ stats, const float* __restrict__ g,
        const float* __restrict__ be, float* __restrict__ x2) {
    int o = blockIdx.x * 256 + threadIdx.x;
    int c = o & 127; int bp = o >> 7;
    float mu = stats[c] * (1.f / E);
    float var = stats[128 + c] * (1.f / E) - mu * mu;
    float sc = g[c] * rsqrtf(var + EPS);
    float sh = be[c] - mu * sc;
    float m = -INFINITY;
#pragma unroll
    for (int j = 0; j < KNN; ++j)
        m = fmaxf(m, fmaf(z3[((size_t)bp * KNN + j) * 128 + c], sc, sh));
    x2[o] = m;
}

// ---------------------------------------------------------------- l1 (direct-fragment split-bf16 MFMA)
__global__ __launch_bounds__(256) void k_l1m(
        const unsigned short* __restrict__ x1h, const unsigned short* __restrict__ x1l,
        const unsigned short* __restrict__ x2h, const unsigned short* __restrict__ x2l,
        const unsigned short* __restrict__ wth, const unsigned short* __restrict__ wtl,
        const float* __restrict__ bias, float* __restrict__ stats,
        float* __restrict__ pmax, float* __restrict__ pmin) {
    __shared__ float red[2 * 128 * 4];
    int tid = threadIdx.x;
    int brow = blockIdx.x & 255;
    int bcol = blockIdx.x >> 8;
    int row0 = brow << 7, col0 = bcol << 7;
    int wv = tid >> 6, lane = tid & 63;
    int wm = wv >> 1, wn = wv & 1;
    int l15 = lane & 15, quad = lane >> 4;
    f32x4 acc[4][4];
#pragma unroll
    for (int i = 0; i < 4; ++i)
#pragma unroll
        for (int j = 0; j < 4; ++j) acc[i][j] = (f32x4)0.f;

#pragma unroll
    for (int k0 = 0; k0 < 192; k0 += 32) {
        const unsigned short* ah = (k0 < 64) ? x1h : x2h;
        const unsigned short* al = (k0 < 64) ? x1l : x2l;
        int astr = (k0 < 64) ? 64 : 128;
        int aoff = (k0 < 64) ? k0 : (k0 - 64);
        bf16x8 afh[4], afl[4], bfh[4], bfl[4];
#pragma unroll
        for (int i = 0; i < 4; ++i) {
            size_t o = (size_t)(row0 + wm * 64 + i * 16 + l15) * astr + aoff + quad * 8;
            afh[i] = *(const bf16x8*)&ah[o];
            afl[i] = *(const bf16x8*)&al[o];
        }
#pragma unroll
        for (int j = 0; j < 4; ++j) {
            size_t wo = (size_t)(col0 + wn * 64 + j * 16 + l15) * 192 + k0 + quad * 8;
            bfh[j] = *(const bf16x8*)&wth[wo];
            bfl[j] = *(const bf16x8*)&wtl[wo];
        }
#pragma unroll
        for (int i = 0; i < 4; ++i)
#pragma unroll
            for (int j = 0; j < 4; ++j) {
                acc[i][j] = __builtin_amdgcn_mfma_f32_16x16x32_bf16(afh[i], bfh[j], acc[i][j], 0, 0, 0);
                acc[i][j] = __builtin_amdgcn_mfma_f32_16x16x32_bf16(afh[i], bfl[j], acc[i][j], 0, 0, 0);
                acc[i][j] = __builtin_amdgcn_mfma_f32_16x16x32_bf16(afl[i], bfh[j], acc[i][j], 0, 0, 0);
            }
    }
    // epilogue: bias + ReLU, per-col sum/sumsq/max/min (h never materialized)
#pragma unroll
    for (int j = 0; j < 4; ++j) {
        int colL = wn * 64 + j * 16 + l15;
        float bl = bias[col0 + colL];
        float s1 = 0.f, s2 = 0.f, mx = 0.f, mn = INFINITY;
#pragma unroll
        for (int i = 0; i < 4; ++i)
#pragma unroll
            for (int r = 0; r < 4; ++r) {
                float v = fmaxf(acc[i][j][r] + bl, 0.f);
                s1 += v; s2 = fmaf(v, v, s2);
                mx = fmaxf(mx, v); mn = fminf(mn, v);
            }
        s1 += __shfl_xor(s1, 16, 64); s1 += __shfl_xor(s1, 32, 64);
        s2 += __shfl_xor(s2, 16, 64); s2 += __shfl_xor(s2, 32, 64);
        mx = fmaxf(mx, __shfl_xor(mx, 16, 64)); mx = fmaxf(mx, __shfl_xor(mx, 32, 64));
        mn = fminf(mn, __shfl_xor(mn, 16, 64)); mn = fminf(mn, __shfl_xor(mn, 32, 64));
        if (quad == 0) {
            float* rp = &red[(wm * 128 + colL) * 4];
            rp[0] = s1; rp[1] = s2; rp[2] = mx; rp[3] = mn;
        }
    }
    __syncthreads();
    if (tid < 128) {
        const float* r0 = &red[tid * 4];
        const float* r1 = &red[(128 + tid) * 4];
        int bb = row0 >> 11;
        atomicAdd(&stats[col0 + tid], r0[0] + r1[0]);
        atomicAdd(&stats[1024 + col0 + tid], r0[1] + r1[1]);
        atomicMax((unsigned int*)&pmax[bb * 1024 + col0 + tid],
                  __float_as_uint(fmaxf(r0[2], r1[2])));
        atomicMin((unsigned int*)&pmin[bb * 1024 + col0 + tid],
                  __float_as_uint(fminf(r0[3], r1[3])));
    }
}

// ---------------------------------------------------------------- pooled p = BN(max or min)
__global__ void k_pool(const float* __restrict__ stats, const float* __restrict__ g,
                       const float* __restrict__ be, const float* __restrict__ pmax,
                       const float* __restrict__ pmin, float* __restrict__ p) {
    int o = blockIdx.x * 256 + threadIdx.x;   // 16384
    int c = o & 1023;
    float mu = stats[c] * (1.f / BP);
    float var = stats[1024 + c] * (1.f / BP) - mu * mu;
    float sc = g[c] * rsqrtf(var + EPS);
    float sh = be[c] - mu * sc;
    float v = (sc >= 0.f) ? pmax[o] : pmin[o];
    p[o] = fmaf(v, sc, sh);
}

// ---------------------------------------------------------------- head
__global__ __launch_bounds__(256) void k_m1(const float* __restrict__ p,
        const float* __restrict__ w, const float* __restrict__ bias,
        float* __restrict__ t1, float* __restrict__ stats) {
    int o = blockIdx.x * 256 + threadIdx.x;   // 8192
    int c = o & 511, b = o >> 9;
    const float* pr = p + (b << 10);
    float acc = bias[c];
    for (int k = 0; k < 1024; ++k) acc = fmaf(pr[k], w[k * 512 + c], acc);
    acc = fmaxf(acc, 0.f);
    t1[o] = acc;
    atomicAdd(&stats[c], acc);
    atomicAdd(&stats[512 + c], acc * acc);
}

__global__ __launch_bounds__(256) void k_m2(const float* __restrict__ t1,
        const float* __restrict__ stats5, const float* __restrict__ g,
        const float* __restrict__ be, const float* __restrict__ w,
        const float* __restrict__ bias, float* __restrict__ t2,
        float* __restrict__ stats6) {
    __shared__ float scl[512], shf[512];
    int tid = threadIdx.x;
    for (int t = tid; t < 512; t += 256) {
        float mu = stats5[t] * (1.f / 16.f);
        float var = stats5[512 + t] * (1.f / 16.f) - mu * mu;
        float sc = g[t] * rsqrtf(var + EPS);
        scl[t] = sc; shf[t] = be[t] - mu * sc;
    }
    __syncthreads();
    int o = blockIdx.x * 256 + tid;   // 4096
    int c = o & 255, b = o >> 8;
    const float* tr = t1 + (b << 9);
    float acc = bias[c];
    for (int k = 0; k < 512; ++k) {
        float u = fmaf(tr[k], scl[k], shf[k]);
        acc = fmaf(u, w[k * 256 + c], acc);
    }
    acc = fmaxf(acc, 0.f);
    t2[o] = acc;
    atomicAdd(&stats6[c], acc);
    atomicAdd(&stats6[256 + c], acc * acc);
}

__global__ __launch_bounds__(256) void k_m3(const float* __restrict__ t2,
        const float* __restrict__ stats6, const float* __restrict__ g,
        const float* __restrict__ be, const float* __restrict__ w,
        const float* __restrict__ bias, float* __restrict__ out) {
    __shared__ float scl[256], shf[256];
    int tid = threadIdx.x;
    {
        float mu = stats6[tid] * (1.f / 16.f);
        float var = stats6[256 + tid] * (1.f / 16.f) - mu * mu;
        float sc = g[tid] * rsqrtf(var + EPS);
        scl[tid] = sc; shf[tid] = be[tid] - mu * sc;
    }
    __syncthreads();
    if (tid < 32) {
        int c = tid & 1, b = tid >> 1;
        const float* tr = t2 + (b << 8);
        float acc = bias[c];
        for (int k = 0; k < 256; ++k) {
            float u = fmaf(tr[k], scl[k], shf[k]);
            acc = fmaf(u, w[k * 2 + c], acc);
        }
        out[tid] = acc;
    }
}

// ================================================================ launch
extern "C" void kernel_launch(void* const* d_in, const int* in_sizes, int n_in,
                              void* d_out, int out_size, void* d_ws, size_t ws_size,
                              hipStream_t stream) {
    const float* pos  = (const float*)d_in[0];
    const float* c1w0 = (const float*)d_in[1];
    const float* c1b0 = (const float*)d_in[2];
    const float* c1g0 = (const float*)d_in[3];
    const float* c1e0 = (const float*)d_in[4];
    const float* c1w1 = (const float*)d_in[5];
    const float* c1b1 = (const float*)d_in[6];
    const float* c1g1 = (const float*)d_in[7];
    const float* c1e1 = (const float*)d_in[8];
    const float* c1w2 = (const float*)d_in[9];
    const float* c1b2 = (const float*)d_in[10];
    const float* c1g2 = (const float*)d_in[11];
    const float* c1e2 = (const float*)d_in[12];
    const float* c2w  = (const float*)d_in[13];
    const float* c2b  = (const float*)d_in[14];
    const float* c2g  = (const float*)d_in[15];
    const float* c2e  = (const float*)d_in[16];
    const float* l1w  = (const float*)d_in[17];
    const float* l1b  = (const float*)d_in[18];
    const float* l1g  = (const float*)d_in[19];
    const float* l1e  = (const float*)d_in[20];
    const float* m1w  = (const float*)d_in[21];
    const float* m1b  = (const float*)d_in[22];
    const float* m1g  = (const float*)d_in[23];
    const float* m1e  = (const float*)d_in[24];
    const float* m2w  = (const float*)d_in[25];
    const float* m2b  = (const float*)d_in[26];
    const float* m2g  = (const float*)d_in[27];
    const float* m2e  = (const float*)d_in[28];
    const float* m3w  = (const float*)d_in[29];
    const float* m3b  = (const float*)d_in[30];
    float* out = (float*)d_out;

    char* ws = (char*)d_ws;
    size_t off = 0;
    auto alloc = [&](size_t bytes) {
        size_t r = off; off = (off + bytes + 255) & ~(size_t)255; return r;
    };
    float* stats = (float*)(ws + alloc(ST_TOTAL * 4));
    float* pmax  = (float*)(ws + alloc(16 * 1024 * 4));
    float* pmin  = (float*)(ws + alloc(16 * 1024 * 4));
    float* pbuf  = (float*)(ws + alloc(16 * 1024 * 4));
    float* t1    = (float*)(ws + alloc(16 * 512 * 4));
    float* t2    = (float*)(ws + alloc(16 * 256 * 4));
    float* sq2   = (float*)(ws + alloc((size_t)BP * 4));
    float* part  = (float*)(ws + alloc((size_t)(E / 64) * 128 * 4));  // up to 2560 blocks x 128
    unsigned short* wthL = (unsigned short*)(ws + alloc((size_t)192 * 1024 * 2));
    unsigned short* wtlL = (unsigned short*)(ws + alloc((size_t)192 * 1024 * 2));
    unsigned short* wdh  = (unsigned short*)(ws + alloc((size_t)128 * 64 * 2));
    unsigned short* wdl  = (unsigned short*)(ws + alloc((size_t)128 * 64 * 2));
    unsigned short* w1h  = (unsigned short*)(ws + alloc((size_t)128 * 64 * 2));
    unsigned short* w1l  = (unsigned short*)(ws + alloc((size_t)128 * 64 * 2));
    unsigned short* wf1h = (unsigned short*)(ws + alloc((size_t)64 * 64 * 2));
    unsigned short* wf1l = (unsigned short*)(ws + alloc((size_t)64 * 64 * 2));
    unsigned short* wf2h = (unsigned short*)(ws + alloc((size_t)64 * 64 * 2));
    unsigned short* wf2l = (unsigned short*)(ws + alloc((size_t)64 * 64 * 2));
    float* bias2a = (float*)(ws + alloc(64 * 4));
    float* bias2b = (float*)(ws + alloc(64 * 4));
    int*   idx1  = (int*)  (ws + alloc((size_t)E * 4));
    int*   idx2  = (int*)  (ws + alloc((size_t)E * 4));
    float* x1    = (float*)(ws + alloc((size_t)BP * 64 * 4));
    float* x2    = (float*)(ws + alloc((size_t)BP * 128 * 4));
    float* zA    = (float*)(ws + alloc((size_t)E * 128 * 4)); // hosts z0/z1 bf16 pairs, later z3 fp32
    float* zB    = (float*)(ws + alloc((size_t)E * 64 * 4));  // hosts z2 bf16 pair, later knn2 scratch
    // zA aliases: z0h/z0l (21MB each) then z1h/z1l; all dead before z3 (ec2 out) overwrites
    unsigned short* z0h = (unsigned short*)zA;
    unsigned short* z0l = z0h + (size_t)E * 64;
    unsigned short* z1h = z0l + (size_t)E * 64;
    unsigned short* z1l = z1h + (size_t)E * 64;
    // zB aliases: z2h/z2l (dead after ec1_fin), then knn2 scratch overwrites
    unsigned short* z2h = (unsigned short*)zB;
    unsigned short* z2l = z2h + (size_t)E * 64;
    unsigned short* x1h = (unsigned short*)zB;
    unsigned short* x1l = x1h + (size_t)BP * 64;
    float* cand_d = (float*)(x1l + (size_t)BP * 64);
    int*   cand_i = (int*)(cand_d + (size_t)BP * QC2 * KNN);
    unsigned short* x2h = (unsigned short*)(cand_i + (size_t)BP * QC2 * KNN);
    unsigned short* x2l = x2h + (size_t)BP * 128;

    (void)in_sizes; (void)n_in; (void)out_size; (void)ws_size;

    k_init<<<64, 256, 0, stream>>>(stats, pmax, pmin);
    k_wsplit<<<(192 * 1024 + 255) / 256, 256, 0, stream>>>(l1w, wthL, wtlL, 192, 1024);
    k_wprep2<<<(64 * 128 + 255) / 256, 256, 0, stream>>>(c2w, wdh, wdl, w1h, w1l);
    k_knn1<<<B * 32, 256, 0, stream>>>(pos, idx1);
    k_ec1_l0<<<E / 256, 256, 0, stream>>>(pos, idx1, c1w0, c1b0, z0h, z0l, part);
    k_redstat<<<128, 256, 0, stream>>>(part, stats + ST0, E / 256);
    k_wfold<<<64, 64, 0, stream>>>(stats + ST0, c1g0, c1e0, c1w1, c1b1,
                                   wf1h, wf1l, bias2a, 1.f / E);
    k_lin64m<<<E / 128, 128, 0, stream>>>(z0h, z0l, wf1h, wf1l, bias2a,
                                          z1h, z1l, part);
    k_redstat<<<128, 256, 0, stream>>>(part, stats + ST1, E / 128);
    k_wfold<<<64, 64, 0, stream>>>(stats + ST1, c1g1, c1e1, c1w2, c1b2,
                                   wf2h, wf2l, bias2b, 1.f / E);
    k_lin64m<<<E / 128, 128, 0, stream>>>(z1h, z1l, wf2h, wf2l, bias2b,
                                          z2h, z2l, part);
    k_redstat<<<128, 256, 0, stream>>>(part, stats + ST2, E / 128);
    k_ec1_fin<<<BP * 64 / 256, 256, 0, stream>>>(z2h, z2l, stats + ST2, c1g2, c1e2,
                                                 x1, sq2);
    k_xsplit<<<BP * 64 / 256, 256, 0, stream>>>(x1, x1h, x1l);
    k_knn2<<<B * 32 * QC2, 128, 0, stream>>>(x1h, x1l, sq2, cand_d, cand_i);
    k_knn2m<<<BP / 256, 256, 0, stream>>>(cand_d, cand_i, idx2);
    k_ec2m<<<E / 128, 256, 0, stream>>>(x1h, x1l, idx2, wdh, wdl, w1h, w1l,
                                        c2b, zA, stats + ST3);
    k_ec2_fin<<<BP * 128 / 256, 256, 0, stream>>>(zA, stats + ST3, c2g, c2e, x2);
    k_xsplit<<<BP * 128 / 256, 256, 0, stream>>>(x2, x2h, x2l);
    k_l1m<<<256 * 8, 256, 0, stream>>>(x1h, x1l, x2h, x2l, wthL, wtlL, l1b,
                                       stats + ST4, pmax, pmin);
    k_pool<<<64, 256, 0, stream>>>(stats + ST4, l1g, l1e, pmax, pmin, pbuf);
    k_m1<<<32, 256, 0, stream>>>(pbuf, m1w, m1b, t1, stats + ST5);
    k_m2<<<16, 256, 0, stream>>>(t1, stats + ST5, m1g, m1e, m2w, m2b, t2, stats + ST6);
    k_m3<<<1, 256, 0, stream>>>(t2, stats + ST6, m2g, m2e, m3w, m3b, out);
}

// Round 17
// 635.777 us; speedup vs baseline: 1.0383x; 1.0383x over previous
//
#include <hip/hip_runtime.h>
#include <cmath>

constexpr int B = 16, P = 2048, KNN = 5;
constexpr int BP = B * P;           // 32768
constexpr int E = BP * KNN;         // 163840
constexpr float EPS = 1e-5f;
constexpr int QC2 = 2;              // q-chunks for knn2 (1024 blocks = 4/CU, longer scan streams)

// stats layout (floats): per stage [sum[C] | sumsq[C]]
constexpr int ST0 = 0;        // 64ch -> 128
constexpr int ST1 = 128;      // 64ch
constexpr int ST2 = 256;      // 64ch
constexpr int ST3 = 384;      // 128ch -> 256
constexpr int ST4 = 640;      // 1024ch -> 2048
constexpr int ST5 = 2688;     // 512ch -> 1024
constexpr int ST6 = 3712;     // 256ch -> 512
constexpr int ST_TOTAL = 4224;

typedef __attribute__((ext_vector_type(8))) short bf16x8;
typedef __attribute__((ext_vector_type(4))) float f32x4;

__device__ inline unsigned short f2bf(float x) {
    unsigned u = __float_as_uint(x);
    unsigned r = (u + 0x7FFFu + ((u >> 16) & 1u)) >> 16;
    return (unsigned short)r;
}
__device__ inline float bf2f(unsigned short h) {
    return __uint_as_float(((unsigned)h) << 16);
}
// split x into hi (bf16) and lo (bf16 of residual): x ~= hi + lo, err ~2^-18 rel
__device__ inline void split2bf(float x, unsigned short& h, unsigned short& l) {
    unsigned short hh = f2bf(x);
    h = hh;
    l = f2bf(x - bf2f(hh));
}

// branch-free sorted-5 insertion (ascending); constant indices -> stays in VGPRs.
__device__ inline void ins5(float d, int qi, float bd[KNN], int bi[KNN]) {
    bool c0 = d < bd[0], c1 = d < bd[1], c2 = d < bd[2], c3 = d < bd[3], c4 = d < bd[4];
    bd[4] = c3 ? bd[3] : (c4 ? d : bd[4]);  bi[4] = c3 ? bi[3] : (c4 ? qi : bi[4]);
    bd[3] = c2 ? bd[2] : (c3 ? d : bd[3]);  bi[3] = c2 ? bi[2] : (c3 ? qi : bi[3]);
    bd[2] = c1 ? bd[1] : (c2 ? d : bd[2]);  bi[2] = c1 ? bi[1] : (c2 ? qi : bi[2]);
    bd[1] = c0 ? bd[0] : (c1 ? d : bd[1]);  bi[1] = c0 ? bi[0] : (c1 ? qi : bi[1]);
    bd[0] = c0 ? d : bd[0];                 bi[0] = c0 ? qi : bi[0];
}
// insertion with lexicographic (d, qi) tie-break: keep lower q on exact fp tie
__device__ inline void ins5t(float d, int qi, float bd[KNN], int bi[KNN]) {
    bool c0 = (d < bd[0]) || (d == bd[0] && qi < bi[0]);
    bool c1 = (d < bd[1]) || (d == bd[1] && qi < bi[1]);
    bool c2 = (d < bd[2]) || (d == bd[2] && qi < bi[2]);
    bool c3 = (d < bd[3]) || (d == bd[3] && qi < bi[3]);
    bool c4 = (d < bd[4]) || (d == bd[4] && qi < bi[4]);
    bd[4] = c3 ? bd[3] : (c4 ? d : bd[4]);  bi[4] = c3 ? bi[3] : (c4 ? qi : bi[4]);
    bd[3] = c2 ? bd[2] : (c3 ? d : bd[3]);  bi[3] = c2 ? bi[2] : (c3 ? qi : bi[3]);
    bd[2] = c1 ? bd[1] : (c2 ? d : bd[2]);  bi[2] = c1 ? bi[1] : (c2 ? qi : bi[2]);
    bd[1] = c0 ? bd[0] : (c1 ? d : bd[1]);  bi[1] = c0 ? bi[0] : (c1 ? qi : bi[1]);
    bd[0] = c0 ? d : bd[0];                 bi[0] = c0 ? qi : bi[0];
}

// ---------------------------------------------------------------- init
__global__ void k_init(float* __restrict__ stats, float* __restrict__ pmax,
                       float* __restrict__ pmin) {
    int i = blockIdx.x * 256 + threadIdx.x;   // grid covers 16384
    if (i < ST_TOTAL) stats[i] = 0.f;
    if (i < B * 1024) { pmax[i] = 0.f; pmin[i] = INFINITY; }
}

// ---------------------------------------------------------------- deterministic partial reducer
__global__ __launch_bounds__(256) void k_redstat(const float* __restrict__ part,
        float* __restrict__ stats, int nblk) {
    __shared__ float r[256];
    int slot = blockIdx.x;
    float s = 0.f;
    for (int i = threadIdx.x; i < nblk; i += 256)
        s += part[(size_t)i * 128 + slot];
    r[threadIdx.x] = s; __syncthreads();
    for (int o = 128; o; o >>= 1) {
        if (threadIdx.x < o) r[threadIdx.x] += r[threadIdx.x + o];
        __syncthreads();
    }
    if (threadIdx.x == 0) stats[slot] = r[0];
}

// ---------------------------------------------------------------- weight pre-split: w[K][N] fp32 -> wt{h,l}[N][K] bf16
__global__ void k_wsplit(const float* __restrict__ w, unsigned short* __restrict__ th,
                         unsigned short* __restrict__ tl, int K, int N) {
    int i = blockIdx.x * 256 + threadIdx.x;
    if (i >= K * N) return;
    int k = i / N, n = i - k * N;          // read coalesced over n
    float f = w[i];
    unsigned short h = f2bf(f);
    th[(size_t)n * K + k] = h;
    tl[(size_t)n * K + k] = f2bf(f - bf2f(h));
}

// ---------------------------------------------------------------- BN-fold: wf[n][k] = scl[k]*w[k][n]; bias2 = bias + shf.w
__global__ __launch_bounds__(64) void k_wfold(const float* __restrict__ stats,
        const float* __restrict__ g, const float* __restrict__ be,
        const float* __restrict__ w, const float* __restrict__ bias,
        unsigned short* __restrict__ wfh, unsigned short* __restrict__ wfl,
        float* __restrict__ bias2, float invN) {
    __shared__ float red[64];
    int n = blockIdx.x, k = threadIdx.x;
    float mu = stats[k] * invN;
    float var = stats[64 + k] * invN - mu * mu;
    float sc = g[k] * rsqrtf(var + EPS);
    float sh = be[k] - mu * sc;
    float wv = w[k * 64 + n];
    float wf = sc * wv;
    unsigned short h, l;
    split2bf(wf, h, l);
    wfh[n * 64 + k] = h; wfl[n * 64 + k] = l;
    red[k] = sh * wv; __syncthreads();
    for (int o = 32; o; o >>= 1) {
        if (k < o) red[k] += red[k + o];
        __syncthreads();
    }
    if (k == 0) bias2[n] = bias[n] + red[0];
}

// ---------------------------------------------------------------- ec2 weight prep: W0-W1 and W1, transposed bf16 hi/lo
__global__ void k_wprep2(const float* __restrict__ w,   // c2w [128][128]
        unsigned short* __restrict__ wdh, unsigned short* __restrict__ wdl,
        unsigned short* __restrict__ w1h, unsigned short* __restrict__ w1l) {
    int i = blockIdx.x * 256 + threadIdx.x;  // 64*128
    if (i >= 64 * 128) return;
    int k = i >> 7, n = i & 127;
    float w0 = w[k * 128 + n];
    float w1 = w[(64 + k) * 128 + n];
    float wd = w0 - w1;
    unsigned short h, l;
    split2bf(wd, h, l); wdh[n * 64 + k] = h; wdl[n * 64 + k] = l;
    split2bf(w1, h, l); w1h[n * 64 + k] = h; w1l[n * 64 + k] = l;
}

// ---------------------------------------------------------------- x pre-split (same layout): fp32 [N] -> bf16 hi/lo
__global__ void k_xsplit(const float* __restrict__ x, unsigned short* __restrict__ xh,
                         unsigned short* __restrict__ xl) {
    int i = blockIdx.x * 256 + threadIdx.x;
    float f = x[i];
    unsigned short h, l;
    split2bf(f, h, l);
    xh[i] = h; xl[i] = l;
}

// ---------------------------------------------------------------- kNN on pos (D=3)
__global__ __launch_bounds__(256) void k_knn1(const float* __restrict__ pos,
                                              int* __restrict__ idx1) {
    __shared__ float4 qt[2048];   // all q staged once (32 KB)
    int b = blockIdx.x >> 5;
    int p0 = (blockIdx.x & 31) << 6;
    const float* posb = pos + (size_t)b * P * 3;
#pragma unroll
    for (int t = 0; t < 8; ++t) {
        int q = (t << 8) + threadIdx.x;
        float qx = posb[q * 3 + 0], qy = posb[q * 3 + 1], qz = posb[q * 3 + 2];
        qt[q] = make_float4(qx, qy, qz, qx * qx + qy * qy + qz * qz);
    }
    __syncthreads();
    int pl = threadIdx.x >> 2, sub = threadIdx.x & 3;
    int p = p0 + pl;
    float4 me = qt[p];
    float x = me.x, y = me.y, z = me.z, sqp = me.w;
    float bd[KNN]; int bi[KNN];
#pragma unroll
    for (int i = 0; i < KNN; ++i) { bd[i] = INFINITY; bi[i] = 0; }
    for (int j0 = 0; j0 < 512; j0 += 8) {
        float4 v[8];
#pragma unroll
        for (int u = 0; u < 8; ++u) v[u] = qt[((j0 + u) << 2) | sub];
#pragma unroll
        for (int u = 0; u < 8; ++u) {
            float dot = x * v[u].x + y * v[u].y + z * v[u].z;
            float d2 = sqp + v[u].w - 2.f * dot;
            if (d2 < bd[KNN - 1]) ins5(d2, ((j0 + u) << 2) | sub, bd, bi);
        }
    }
    // butterfly merge across the 4 subs; snapshot-then-insert
#pragma unroll
    for (int w = 1; w <= 2; w <<= 1) {
        float od[KNN]; int oi[KNN];
#pragma unroll
        for (int i = 0; i < KNN; ++i) {
            od[i] = __shfl_xor(bd[i], w, 64);
            oi[i] = __shfl_xor(bi[i], w, 64);
        }
#pragma unroll
        for (int i = 0; i < KNN; ++i) ins5t(od[i], oi[i], bd, bi);
    }
    if (sub == 0) {
        size_t o = ((size_t)b * P + p) * KNN;
#pragma unroll
        for (int i = 0; i < KNN; ++i) idx1[o + i] = bi[i];
    }
}

// ---------------------------------------------------------------- edgeconv1 layer0: e[6] @ w[6,64]; bf16 hi/lo out + partials
__global__ __launch_bounds__(256) void k_ec1_l0(const float* __restrict__ pos,
        const int* __restrict__ idx1, const float* __restrict__ w,
        const float* __restrict__ bias, unsigned short* __restrict__ zh,
        unsigned short* __restrict__ zl, float* __restrict__ part) {
    __shared__ float elds[256][6];
    __shared__ float red[256];
    int tid = threadIdx.x;
    int base = blockIdx.x * 256;
    {
        int e = base + tid;
        int bp = e / KNN;
        int bb = bp >> 11;
        int q = idx1[e];
        const float* pi = pos + (size_t)bp * 3;
        const float* pj = pos + ((size_t)(bb << 11) + q) * 3;
        float x0 = pi[0], x1v = pi[1], x2v = pi[2];
        elds[tid][0] = x0; elds[tid][1] = x1v; elds[tid][2] = x2v;
        elds[tid][3] = pj[0] - x0; elds[tid][4] = pj[1] - x1v; elds[tid][5] = pj[2] - x2v;
    }
    int c = tid & 63, lane = tid >> 6;
    float wr[6];
#pragma unroll
    for (int d = 0; d < 6; ++d) wr[d] = w[d * 64 + c];
    float bc = bias[c];
    __syncthreads();
    float s1 = 0.f, s2 = 0.f;
    for (int i = 0; i < 64; ++i) {
        int e = lane + (i << 2);
        float acc = bc;
#pragma unroll
        for (int d = 0; d < 6; ++d) acc = fmaf(elds[e][d], wr[d], acc);
        acc = fmaxf(acc, 0.f);
        unsigned short h, l;
        split2bf(acc, h, l);
        zh[(size_t)(base + e) * 64 + c] = h;
        zl[(size_t)(base + e) * 64 + c] = l;
        s1 += acc; s2 = fmaf(acc, acc, s2);
    }
    red[tid] = s1; __syncthreads();
    if (tid < 64) part[(size_t)blockIdx.x * 128 + tid] =
        red[tid] + red[tid + 64] + red[tid + 128] + red[tid + 192];
    __syncthreads();
    red[tid] = s2; __syncthreads();
    if (tid < 64) part[(size_t)blockIdx.x * 128 + 64 + tid] =
        red[tid] + red[tid + 64] + red[tid + 128] + red[tid + 192];
}

// ---------------------------------------------------------------- 64->64 layer (BN folded into weights; direct-frag MFMA)
__global__ __launch_bounds__(128) void k_lin64m(
        const unsigned short* __restrict__ zinh, const unsigned short* __restrict__ zinl,
        const unsigned short* __restrict__ wfh, const unsigned short* __restrict__ wfl,
        const float* __restrict__ bias2, unsigned short* __restrict__ zouth,
        unsigned short* __restrict__ zoutl, float* __restrict__ part) {
    __shared__ float red[2 * 64 * 2];
    int tid = threadIdx.x;
    int wv = tid >> 6, lane = tid & 63;
    int l15 = lane & 15, quad = lane >> 4;
    int row0 = blockIdx.x * 128 + wv * 64;
    f32x4 acc[4][4];
#pragma unroll
    for (int i = 0; i < 4; ++i)
#pragma unroll
        for (int j = 0; j < 4; ++j) acc[i][j] = (f32x4)0.f;

#pragma unroll
    for (int kc = 0; kc < 2; ++kc) {
        bf16x8 afh[4], afl[4], bfh[4], bfl[4];
#pragma unroll
        for (int i = 0; i < 4; ++i) {
            size_t o = (size_t)(row0 + i * 16 + l15) * 64 + kc * 32 + quad * 8;
            afh[i] = *(const bf16x8*)&zinh[o];
            afl[i] = *(const bf16x8*)&zinl[o];
        }
#pragma unroll
        for (int j = 0; j < 4; ++j) {
            size_t wo = (size_t)(j * 16 + l15) * 64 + kc * 32 + quad * 8;
            bfh[j] = *(const bf16x8*)&wfh[wo];
            bfl[j] = *(const bf16x8*)&wfl[wo];
        }
#pragma unroll
        for (int i = 0; i < 4; ++i)
#pragma unroll
            for (int j = 0; j < 4; ++j) {
                acc[i][j] = __builtin_amdgcn_mfma_f32_16x16x32_bf16(afh[i], bfh[j], acc[i][j], 0, 0, 0);
                acc[i][j] = __builtin_amdgcn_mfma_f32_16x16x32_bf16(afh[i], bfl[j], acc[i][j], 0, 0, 0);
                acc[i][j] = __builtin_amdgcn_mfma_f32_16x16x32_bf16(afl[i], bfh[j], acc[i][j], 0, 0, 0);
            }
    }
    // epilogue: bias + ReLU, bf16 split store, per-col stats
#pragma unroll
    for (int j = 0; j < 4; ++j) {
        int colL = j * 16 + l15;
        float bl = bias2[colL];
        float s1 = 0.f, s2 = 0.f;
#pragma unroll
        for (int i = 0; i < 4; ++i) {
            int row = row0 + i * 16 + quad * 4;
#pragma unroll
            for (int r = 0; r < 4; ++r) {
                float v = fmaxf(acc[i][j][r] + bl, 0.f);
                unsigned short h, l;
                split2bf(v, h, l);
                zouth[(size_t)(row + r) * 64 + colL] = h;
                zoutl[(size_t)(row + r) * 64 + colL] = l;
                s1 += v; s2 = fmaf(v, v, s2);
            }
        }
        s1 += __shfl_xor(s1, 16, 64); s1 += __shfl_xor(s1, 32, 64);
        s2 += __shfl_xor(s2, 16, 64); s2 += __shfl_xor(s2, 32, 64);
        if (quad == 0) {
            red[(wv * 64 + colL) * 2 + 0] = s1;
            red[(wv * 64 + colL) * 2 + 1] = s2;
        }
    }
    __syncthreads();
    if (tid < 64) {
        part[(size_t)blockIdx.x * 128 + tid] =
            red[tid * 2] + red[(64 + tid) * 2];
        part[(size_t)blockIdx.x * 128 + 64 + tid] =
            red[tid * 2 + 1] + red[(64 + tid) * 2 + 1];
    }
}

// ---------------------------------------------------------------- ec1 finalize: BN + max over k -> x1, sq norms (bf16 hi/lo in)
__global__ __launch_bounds__(256) void k_ec1_fin(const unsigned short* __restrict__ z2h,
        const unsigned short* __restrict__ z2l,
        const float* __restrict__ statsIn, const float* __restrict__ g,
        const float* __restrict__ be, float* __restrict__ x1,
        float* __restrict__ sq2) {
    int tid = threadIdx.x;
    int o = blockIdx.x * 256 + tid;
    int c = o & 63; int bp = o >> 6;
    float mu = statsIn[c] * (1.f / E);
    float var = statsIn[64 + c] * (1.f / E) - mu * mu;
    float sc = g[c] * rsqrtf(var + EPS);
    float sh = be[c] - mu * sc;
    float m = -INFINITY;
#pragma unroll
    for (int j = 0; j < KNN; ++j) {
        size_t zo = ((size_t)bp * KNN + j) * 64 + c;
        float v = bf2f(z2h[zo]) + bf2f(z2l[zo]);
        m = fmaxf(m, fmaf(v, sc, sh));
    }
    x1[o] = m;
    float ss = m * m;
#pragma unroll
    for (int off = 32; off; off >>= 1) ss += __shfl_down(ss, off, 64);
    if (c == 0) sq2[bp] = ss;
}

// ---------------------------------------------------------------- kNN2 partial (split-bf16 MFMA Gram + top-5 per q-chunk)
// QC2=2: 1024-q streams per lane -> ins5 fires sub-100% beyond t~320.
__global__ __launch_bounds__(128, 1) void k_knn2(const unsigned short* __restrict__ x1h,
        const unsigned short* __restrict__ x1l, const float* __restrict__ sq2,
        float* __restrict__ cd, int* __restrict__ ci) {
    __shared__ float S[2][32 * 129];   // per-wave key tile, stride 129 (bank rotate)
    int tid = threadIdx.x;
    int wv = tid >> 6, lane = tid & 63;
    int l15 = lane & 15, quad = lane >> 4;
    int qc = blockIdx.x & (QC2 - 1);
    int pt = blockIdx.x >> 1;                 // 16*32 ptiles of 64 rows
    int b = pt >> 5;
    int pw = ((pt & 31) << 6) + wv * 32;      // wave p base within batch
    const size_t xbase = (size_t)b * P * 64;
    float* Sw = &S[wv][0];

    // A fragments (rows pw..pw+31), kept for the whole kernel
    bf16x8 ah[2][2], al[2][2];
#pragma unroll
    for (int i = 0; i < 2; ++i)
#pragma unroll
        for (int kc = 0; kc < 2; ++kc) {
            size_t o = xbase + (size_t)(pw + i * 16 + l15) * 64 + kc * 32 + quad * 8;
            ah[i][kc] = *(const bf16x8*)&x1h[o];
            al[i][kc] = *(const bf16x8*)&x1l[o];
        }

    int half = lane >> 5;      // 0/1: which q-half this lane scans
    int pidx = lane & 31;      // which p row this lane scans
    float bd[KNN]; int bi[KNN];
#pragma unroll
    for (int i = 0; i < KNN; ++i) { bd[i] = INFINITY; bi[i] = 0; }

    int qlo = qc << 10;        // 1024-q chunk
    for (int t = 0; t < 8; ++t) {
        int q0 = qlo + (t << 7);
        float qsv[8];
#pragma unroll
        for (int j = 0; j < 8; ++j) qsv[j] = sq2[b * P + q0 + j * 16 + l15];
        f32x4 acc[2][8];
#pragma unroll
        for (int i = 0; i < 2; ++i)
#pragma unroll
            for (int j = 0; j < 8; ++j) acc[i][j] = (f32x4)0.f;
#pragma unroll
        for (int kc = 0; kc < 2; ++kc) {
            bf16x8 bh[8], bl[8];
#pragma unroll
            for (int j = 0; j < 8; ++j) {
                size_t o = xbase + (size_t)(q0 + j * 16 + l15) * 64 + kc * 32 + quad * 8;
                bh[j] = *(const bf16x8*)&x1h[o];
                bl[j] = *(const bf16x8*)&x1l[o];
            }
#pragma unroll
            for (int i = 0; i < 2; ++i)
#pragma unroll
                for (int j = 0; j < 8; ++j) {
                    acc[i][j] = __builtin_amdgcn_mfma_f32_16x16x32_bf16(ah[i][kc], bh[j], acc[i][j], 0, 0, 0);
                    acc[i][j] = __builtin_amdgcn_mfma_f32_16x16x32_bf16(ah[i][kc], bl[j], acc[i][j], 0, 0, 0);
                    acc[i][j] = __builtin_amdgcn_mfma_f32_16x16x32_bf16(al[i][kc], bh[j], acc[i][j], 0, 0, 0);
                }
        }
        // keys to LDS: S[p_local][q_local] = sq_q - 2*dot (sq_p dropped: row-constant)
#pragma unroll
        for (int i = 0; i < 2; ++i)
#pragma unroll
            for (int j = 0; j < 8; ++j)
#pragma unroll
                for (int r = 0; r < 4; ++r) {
                    int pl = i * 16 + quad * 4 + r;
                    Sw[pl * 129 + j * 16 + l15] = fmaf(acc[i][j][r], -2.f, qsv[j]);
                }
        // scan own rows (same wave wrote them; DS in-order -> no barrier)
        const float* row = Sw + pidx * 129 + half * 64;
        int qb = q0 + half * 64;
        for (int jj = 0; jj < 64; jj += 4) {
            float k0 = row[jj + 0], k1 = row[jj + 1], k2 = row[jj + 2], k3 = row[jj + 3];
            if (k0 < bd[4]) ins5(k0, qb + jj + 0, bd, bi);
            if (k1 < bd[4]) ins5(k1, qb + jj + 1, bd, bi);
            if (k2 < bd[4]) ins5(k2, qb + jj + 2, bd, bi);
            if (k3 < bd[4]) ins5(k3, qb + jj + 3, bd, bi);
        }
    }
    // merge the two half-lanes (one-directional: half==1's list stays immutable)
#pragma unroll
    for (int i = 0; i < KNN; ++i) {
        float od = __shfl_xor(bd[i], 32, 64);
        int oi = __shfl_xor(bi[i], 32, 64);
        if (half == 0) ins5t(od, oi, bd, bi);
    }
    if (half == 0) {
        size_t o = (((size_t)b * P + pw + pidx) * QC2 + qc) * KNN;
#pragma unroll
        for (int i = 0; i < KNN; ++i) { cd[o + i] = bd[i]; ci[o + i] = bi[i]; }
    }
}

// ---------------------------------------------------------------- kNN2 merge (QC2 sorted chunks of 5 -> 5)
__global__ __launch_bounds__(256) void k_knn2m(const float* __restrict__ cd,
        const int* __restrict__ ci, int* __restrict__ idx2) {
    int bp = blockIdx.x * 256 + threadIdx.x;
    float bd[KNN]; int bi[KNN];
#pragma unroll
    for (int i = 0; i < KNN; ++i) { bd[i] = INFINITY; bi[i] = 0; }
    size_t o = (size_t)bp * QC2 * KNN;
    for (int t = 0; t < QC2 * KNN; ++t) {
        float d2 = cd[o + t]; int qi = ci[o + t];
        if (d2 < bd[KNN - 1]) ins5(d2, qi, bd, bi);
    }
#pragma unroll
    for (int i = 0; i < KNN; ++i) idx2[bp * KNN + i] = bi[i];
}

// ---------------------------------------------------------------- edgeconv2 (direct-fragment split-bf16 MFMA)
__global__ __launch_bounds__(256) void k_ec2m(
        const unsigned short* __restrict__ x1h, const unsigned short* __restrict__ x1l,
        const int* __restrict__ idx2,
        const unsigned short* __restrict__ wdh, const unsigned short* __restrict__ wdl,
        const unsigned short* __restrict__ w1h, const unsigned short* __restrict__ w1l,
        const float* __restrict__ bias, float* __restrict__ zout,
        float* __restrict__ stats) {
    __shared__ float red[2 * 128 * 2];
    int tid = threadIdx.x;
    int base = blockIdx.x * 128;            // first edge
    int bb = base / (P * KNN);              // batch (blocks never straddle: 10240%128==0)
    int wv = tid >> 6, lane = tid & 63;
    int wm = wv >> 1, wn = wv & 1;
    int l15 = lane & 15, quad = lane >> 4;
    // per-lane A rows for this wave's 4 row-tiles
    int rI[4], rJ[4];
#pragma unroll
    for (int i = 0; i < 4; ++i) {
        int e = base + wm * 64 + i * 16 + l15;
        rI[i] = e / KNN;
        rJ[i] = (bb << 11) + idx2[e];
    }
    f32x4 acc[4][4];
#pragma unroll
    for (int i = 0; i < 4; ++i)
#pragma unroll
        for (int j = 0; j < 4; ++j) acc[i][j] = (f32x4)0.f;

#pragma unroll
    for (int s = 0; s < 2; ++s) {
        const unsigned short* bh_ = s ? w1h : wdh;
        const unsigned short* bl_ = s ? w1l : wdl;
#pragma unroll
        for (int kc = 0; kc < 2; ++kc) {
            bf16x8 afh[4], afl[4], bfh[4], bfl[4];
#pragma unroll
            for (int i = 0; i < 4; ++i) {
                int row = s ? rJ[i] : rI[i];
                size_t o = (size_t)row * 64 + kc * 32 + quad * 8;
                afh[i] = *(const bf16x8*)&x1h[o];
                afl[i] = *(const bf16x8*)&x1l[o];
            }
#pragma unroll
            for (int j = 0; j < 4; ++j) {
                size_t wo = (size_t)(wn * 64 + j * 16 + l15) * 64 + kc * 32 + quad * 8;
                bfh[j] = *(const bf16x8*)&bh_[wo];
                bfl[j] = *(const bf16x8*)&bl_[wo];
            }
#pragma unroll
            for (int i = 0; i < 4; ++i)
#pragma unroll
                for (int j = 0; j < 4; ++j) {
                    acc[i][j] = __builtin_amdgcn_mfma_f32_16x16x32_bf16(afh[i], bfh[j], acc[i][j], 0, 0, 0);
                    acc[i][j] = __builtin_amdgcn_mfma_f32_16x16x32_bf16(afh[i], bfl[j], acc[i][j], 0, 0, 0);
                    acc[i][j] = __builtin_amdgcn_mfma_f32_16x16x32_bf16(afl[i], bfh[j], acc[i][j], 0, 0, 0);
                }
        }
    }
    // epilogue: bias + ReLU, write z, per-col stats
#pragma unroll
    for (int j = 0; j < 4; ++j) {
        int colL = wn * 64 + j * 16 + l15;
        float bl = bias[colL];
        float s1 = 0.f, s2 = 0.f;
#pragma unroll
        for (int i = 0; i < 4; ++i) {
            int row = wm * 64 + i * 16 + quad * 4;
#pragma unroll
            for (int r = 0; r < 4; ++r) {
                float v = fmaxf(acc[i][j][r] + bl, 0.f);
                zout[(size_t)(base + row + r) * 128 + colL] = v;
                s1 += v; s2 = fmaf(v, v, s2);
            }
        }
        s1 += __shfl_xor(s1, 16, 64); s1 += __shfl_xor(s1, 32, 64);
        s2 += __shfl_xor(s2, 16, 64); s2 += __shfl_xor(s2, 32, 64);
        if (quad == 0) {
            red[(wm * 128 + colL) * 2 + 0] = s1;
            red[(wm * 128 + colL) * 2 + 1] = s2;
        }
    }
    __syncthreads();
    if (tid < 128) {
        atomicAdd(&stats[tid], red[tid * 2] + red[(128 + tid) * 2]);
        atomicAdd(&stats[128 + tid], red[tid * 2 + 1] + red[(128 + tid) * 2 + 1]);
    }
}

// ---------------------------------------------------------------- ec2 finalize: BN + max over k -> x2
__global__ __launch_bounds__(256) void k_ec2_fin(const float* __restrict__ z3,
        const float* __restrict__ stats, const float* __restrict__ g,
        const float* __restrict__ be, float* __restrict__ x2) {
    int o = blockIdx.x * 256 + threadIdx.x;
    int c = o & 127; int bp = o >> 7;
    float mu = stats[c] * (1.f / E);
    float var = stats[128 + c] * (1.f / E) - mu * mu;
    float sc = g[c] * rsqrtf(var + EPS);
    float sh = be[c] - mu * sc;
    float m = -INFINITY;
#pragma unroll
    for (int j = 0; j < KNN; ++j)
        m = fmaxf(m, fmaf(z3[((size_t)bp * KNN + j) * 128 + c], sc, sh));
    x2[o] = m;
}

// ---------------------------------------------------------------- l1 (direct-fragment split-bf16 MFMA)
__global__ __launch_bounds__(256) void k_l1m(
        const unsigned short* __restrict__ x1h, const unsigned short* __restrict__ x1l,
        const unsigned short* __restrict__ x2h, const unsigned short* __restrict__ x2l,
        const unsigned short* __restrict__ wth, const unsigned short* __restrict__ wtl,
        const float* __restrict__ bias, float* __restrict__ stats,
        float* __restrict__ pmax, float* __restrict__ pmin) {
    __shared__ float red[2 * 128 * 4];
    int tid = threadIdx.x;
    int brow = blockIdx.x & 255;
    int bcol = blockIdx.x >> 8;
    int row0 = brow << 7, col0 = bcol << 7;
    int wv = tid >> 6, lane = tid & 63;
    int wm = wv >> 1, wn = wv & 1;
    int l15 = lane & 15, quad = lane >> 4;
    f32x4 acc[4][4];
#pragma unroll
    for (int i = 0; i < 4; ++i)
#pragma unroll
        for (int j = 0; j < 4; ++j) acc[i][j] = (f32x4)0.f;

#pragma unroll
    for (int k0 = 0; k0 < 192; k0 += 32) {
        const unsigned short* ah = (k0 < 64) ? x1h : x2h;
        const unsigned short* al = (k0 < 64) ? x1l : x2l;
        int astr = (k0 < 64) ? 64 : 128;
        int aoff = (k0 < 64) ? k0 : (k0 - 64);
        bf16x8 afh[4], afl[4], bfh[4], bfl[4];
#pragma unroll
        for (int i = 0; i < 4; ++i) {
            size_t o = (size_t)(row0 + wm * 64 + i * 16 + l15) * astr + aoff + quad * 8;
            afh[i] = *(const bf16x8*)&ah[o];
            afl[i] = *(const bf16x8*)&al[o];
        }
#pragma unroll
        for (int j = 0; j < 4; ++j) {
            size_t wo = (size_t)(col0 + wn * 64 + j * 16 + l15) * 192 + k0 + quad * 8;
            bfh[j] = *(const bf16x8*)&wth[wo];
            bfl[j] = *(const bf16x8*)&wtl[wo];
        }
#pragma unroll
        for (int i = 0; i < 4; ++i)
#pragma unroll
            for (int j = 0; j < 4; ++j) {
                acc[i][j] = __builtin_amdgcn_mfma_f32_16x16x32_bf16(afh[i], bfh[j], acc[i][j], 0, 0, 0);
                acc[i][j] = __builtin_amdgcn_mfma_f32_16x16x32_bf16(afh[i], bfl[j], acc[i][j], 0, 0, 0);
                acc[i][j] = __builtin_amdgcn_mfma_f32_16x16x32_bf16(afl[i], bfh[j], acc[i][j], 0, 0, 0);
            }
    }
    // epilogue: bias + ReLU, per-col sum/sumsq/max/min (h never materialized)
#pragma unroll
    for (int j = 0; j < 4; ++j) {
        int colL = wn * 64 + j * 16 + l15;
        float bl = bias[col0 + colL];
        float s1 = 0.f, s2 = 0.f, mx = 0.f, mn = INFINITY;
#pragma unroll
        for (int i = 0; i < 4; ++i)
#pragma unroll
            for (int r = 0; r < 4; ++r) {
                float v = fmaxf(acc[i][j][r] + bl, 0.f);
                s1 += v; s2 = fmaf(v, v, s2);
                mx = fmaxf(mx, v); mn = fminf(mn, v);
            }
        s1 += __shfl_xor(s1, 16, 64); s1 += __shfl_xor(s1, 32, 64);
        s2 += __shfl_xor(s2, 16, 64); s2 += __shfl_xor(s2, 32, 64);
        mx = fmaxf(mx, __shfl_xor(mx, 16, 64)); mx = fmaxf(mx, __shfl_xor(mx, 32, 64));
        mn = fminf(mn, __shfl_xor(mn, 16, 64)); mn = fminf(mn, __shfl_xor(mn, 32, 64));
        if (quad == 0) {
            float* rp = &red[(wm * 128 + colL) * 4];
            rp[0] = s1; rp[1] = s2; rp[2] = mx; rp[3] = mn;
        }
    }
    __syncthreads();
    if (tid < 128) {
        const float* r0 = &red[tid * 4];
        const float* r1 = &red[(128 + tid) * 4];
        int bb = row0 >> 11;
        atomicAdd(&stats[col0 + tid], r0[0] + r1[0]);
        atomicAdd(&stats[1024 + col0 + tid], r0[1] + r1[1]);
        atomicMax((unsigned int*)&pmax[bb * 1024 + col0 + tid],
                  __float_as_uint(fmaxf(r0[2], r1[2])));
        atomicMin((unsigned int*)&pmin[bb * 1024 + col0 + tid],
                  __float_as_uint(fminf(r0[3], r1[3])));
    }
}

// ---------------------------------------------------------------- pooled p = BN(max or min)
__global__ void k_pool(const float* __restrict__ stats, const float* __restrict__ g,
                       const float* __restrict__ be, const float* __restrict__ pmax,
                       const float* __restrict__ pmin, float* __restrict__ p) {
    int o = blockIdx.x * 256 + threadIdx.x;   // 16384
    int c = o & 1023;
    float mu = stats[c] * (1.f / BP);
    float var = stats[1024 + c] * (1.f / BP) - mu * mu;
    float sc = g[c] * rsqrtf(var + EPS);
    float sh = be[c] - mu * sc;
    float v = (sc >= 0.f) ? pmax[o] : pmin[o];
    p[o] = fmaf(v, sc, sh);
}

// ---------------------------------------------------------------- head
__global__ __launch_bounds__(256) void k_m1(const float* __restrict__ p,
        const float* __restrict__ w, const float* __restrict__ bias,
        float* __restrict__ t1, float* __restrict__ stats) {
    int o = blockIdx.x * 256 + threadIdx.x;   // 8192
    int c = o & 511, b = o >> 9;
    const float* pr = p + (b << 10);
    float acc = bias[c];
    for (int k = 0; k < 1024; ++k) acc = fmaf(pr[k], w[k * 512 + c], acc);
    acc = fmaxf(acc, 0.f);
    t1[o] = acc;
    atomicAdd(&stats[c], acc);
    atomicAdd(&stats[512 + c], acc * acc);
}

__global__ __launch_bounds__(256) void k_m2(const float* __restrict__ t1,
        const float* __restrict__ stats5, const float* __restrict__ g,
        const float* __restrict__ be, const float* __restrict__ w,
        const float* __restrict__ bias, float* __restrict__ t2,
        float* __restrict__ stats6) {
    __shared__ float scl[512], shf[512];
    int tid = threadIdx.x;
    for (int t = tid; t < 512; t += 256) {
        float mu = stats5[t] * (1.f / 16.f);
        float var = stats5[512 + t] * (1.f / 16.f) - mu * mu;
        float sc = g[t] * rsqrtf(var + EPS);
        scl[t] = sc; shf[t] = be[t] - mu * sc;
    }
    __syncthreads();
    int o = blockIdx.x * 256 + tid;   // 4096
    int c = o & 255, b = o >> 8;
    const float* tr = t1 + (b << 9);
    float acc = bias[c];
    for (int k = 0; k < 512; ++k) {
        float u = fmaf(tr[k], scl[k], shf[k]);
        acc = fmaf(u, w[k * 256 + c], acc);
    }
    acc = fmaxf(acc, 0.f);
    t2[o] = acc;
    atomicAdd(&stats6[c], acc);
    atomicAdd(&stats6[256 + c], acc * acc);
}

__global__ __launch_bounds__(256) void k_m3(const float* __restrict__ t2,
        const float* __restrict__ stats6, const float* __restrict__ g,
        const float* __restrict__ be, const float* __restrict__ w,
        const float* __restrict__ bias, float* __restrict__ out) {
    __shared__ float scl[256], shf[256];
    int tid = threadIdx.x;
    {
        float mu = stats6[tid] * (1.f / 16.f);
        float var = stats6[256 + tid] * (1.f / 16.f) - mu * mu;
        float sc = g[tid] * rsqrtf(var + EPS);
        scl[tid] = sc; shf[tid] = be[tid] - mu * sc;
    }
    __syncthreads();
    if (tid < 32) {
        int c = tid & 1, b = tid >> 1;
        const float* tr = t2 + (b << 8);
        float acc = bias[c];
        for (int k = 0; k < 256; ++k) {
            float u = fmaf(tr[k], scl[k], shf[k]);
            acc = fmaf(u, w[k * 2 + c], acc);
        }
        out[tid] = acc;
    }
}

// ================================================================ launch
extern "C" void kernel_launch(void* const* d_in, const int* in_sizes, int n_in,
                              void* d_out, int out_size, void* d_ws, size_t ws_size,
                              hipStream_t stream) {
    const float* pos  = (const float*)d_in[0];
    const float* c1w0 = (const float*)d_in[1];
    const float* c1b0 = (const float*)d_in[2];
    const float* c1g0 = (const float*)d_in[3];
    const float* c1e0 = (const float*)d_in[4];
    const float* c1w1 = (const float*)d_in[5];
    const float* c1b1 = (const float*)d_in[6];
    const float* c1g1 = (const float*)d_in[7];
    const float* c1e1 = (const float*)d_in[8];
    const float* c1w2 = (const float*)d_in[9];
    const float* c1b2 = (const float*)d_in[10];
    const float* c1g2 = (const float*)d_in[11];
    const float* c1e2 = (const float*)d_in[12];
    const float* c2w  = (const float*)d_in[13];
    const float* c2b  = (const float*)d_in[14];
    const float* c2g  = (const float*)d_in[15];
    const float* c2e  = (const float*)d_in[16];
    const float* l1w  = (const float*)d_in[17];
    const float* l1b  = (const float*)d_in[18];
    const float* l1g  = (const float*)d_in[19];
    const float* l1e  = (const float*)d_in[20];
    const float* m1w  = (const float*)d_in[21];
    const float* m1b  = (const float*)d_in[22];
    const float* m1g  = (const float*)d_in[23];
    const float* m1e  = (const float*)d_in[24];
    const float* m2w  = (const float*)d_in[25];
    const float* m2b  = (const float*)d_in[26];
    const float* m2g  = (const float*)d_in[27];
    const float* m2e  = (const float*)d_in[28];
    const float* m3w  = (const float*)d_in[29];
    const float* m3b  = (const float*)d_in[30];
    float* out = (float*)d_out;

    char* ws = (char*)d_ws;
    size_t off = 0;
    auto alloc = [&](size_t bytes) {
        size_t r = off; off = (off + bytes + 255) & ~(size_t)255; return r;
    };
    float* stats = (float*)(ws + alloc(ST_TOTAL * 4));
    float* pmax  = (float*)(ws + alloc(16 * 1024 * 4));
    float* pmin  = (float*)(ws + alloc(16 * 1024 * 4));
    float* pbuf  = (float*)(ws + alloc(16 * 1024 * 4));
    float* t1    = (float*)(ws + alloc(16 * 512 * 4));
    float* t2    = (float*)(ws + alloc(16 * 256 * 4));
    float* sq2   = (float*)(ws + alloc((size_t)BP * 4));
    float* part  = (float*)(ws + alloc((size_t)(E / 64) * 128 * 4));  // up to 2560 blocks x 128
    unsigned short* wthL = (unsigned short*)(ws + alloc((size_t)192 * 1024 * 2));
    unsigned short* wtlL = (unsigned short*)(ws + alloc((size_t)192 * 1024 * 2));
    unsigned short* wdh  = (unsigned short*)(ws + alloc((size_t)128 * 64 * 2));
    unsigned short* wdl  = (unsigned short*)(ws + alloc((size_t)128 * 64 * 2));
    unsigned short* w1h  = (unsigned short*)(ws + alloc((size_t)128 * 64 * 2));
    unsigned short* w1l  = (unsigned short*)(ws + alloc((size_t)128 * 64 * 2));
    unsigned short* wf1h = (unsigned short*)(ws + alloc((size_t)64 * 64 * 2));
    unsigned short* wf1l = (unsigned short*)(ws + alloc((size_t)64 * 64 * 2));
    unsigned short* wf2h = (unsigned short*)(ws + alloc((size_t)64 * 64 * 2));
    unsigned short* wf2l = (unsigned short*)(ws + alloc((size_t)64 * 64 * 2));
    float* bias2a = (float*)(ws + alloc(64 * 4));
    float* bias2b = (float*)(ws + alloc(64 * 4));
    int*   idx1  = (int*)  (ws + alloc((size_t)E * 4));
    int*   idx2  = (int*)  (ws + alloc((size_t)E * 4));
    float* x1    = (float*)(ws + alloc((size_t)BP * 64 * 4));
    float* x2    = (float*)(ws + alloc((size_t)BP * 128 * 4));
    float* zA    = (float*)(ws + alloc((size_t)E * 128 * 4)); // hosts z0/z1 bf16 pairs, later z3 fp32
    float* zB    = (float*)(ws + alloc((size_t)E * 64 * 4));  // hosts z2 bf16 pair, later knn2 scratch
    // zA aliases: z0h/z0l (21MB each) then z1h/z1l; all dead before z3 (ec2 out) overwrites
    unsigned short* z0h = (unsigned short*)zA;
    unsigned short* z0l = z0h + (size_t)E * 64;
    unsigned short* z1h = z0l + (size_t)E * 64;
    unsigned short* z1l = z1h + (size_t)E * 64;
    // zB aliases: z2h/z2l (dead after ec1_fin), then knn2 scratch overwrites
    unsigned short* z2h = (unsigned short*)zB;
    unsigned short* z2l = z2h + (size_t)E * 64;
    unsigned short* x1h = (unsigned short*)zB;
    unsigned short* x1l = x1h + (size_t)BP * 64;
    float* cand_d = (float*)(x1l + (size_t)BP * 64);
    int*   cand_i = (int*)(cand_d + (size_t)BP * QC2 * KNN);
    unsigned short* x2h = (unsigned short*)(cand_i + (size_t)BP * QC2 * KNN);
    unsigned short* x2l = x2h + (size_t)BP * 128;

    (void)in_sizes; (void)n_in; (void)out_size; (void)ws_size;

    k_init<<<64, 256, 0, stream>>>(stats, pmax, pmin);
    k_wsplit<<<(192 * 1024 + 255) / 256, 256, 0, stream>>>(l1w, wthL, wtlL, 192, 1024);
    k_wprep2<<<(64 * 128 + 255) / 256, 256, 0, stream>>>(c2w, wdh, wdl, w1h, w1l);
    k_knn1<<<B * 32, 256, 0, stream>>>(pos, idx1);
    k_ec1_l0<<<E / 256, 256, 0, stream>>>(pos, idx1, c1w0, c1b0, z0h, z0l, part);
    k_redstat<<<128, 256, 0, stream>>>(part, stats + ST0, E / 256);
    k_wfold<<<64, 64, 0, stream>>>(stats + ST0, c1g0, c1e0, c1w1, c1b1,
                                   wf1h, wf1l, bias2a, 1.f / E);
    k_lin64m<<<E / 128, 128, 0, stream>>>(z0h, z0l, wf1h, wf1l, bias2a,
                                          z1h, z1l, part);
    k_redstat<<<128, 256, 0, stream>>>(part, stats + ST1, E / 128);
    k_wfold<<<64, 64, 0, stream>>>(stats + ST1, c1g1, c1e1, c1w2, c1b2,
                                   wf2h, wf2l, bias2b, 1.f / E);
    k_lin64m<<<E / 128, 128, 0, stream>>>(z1h, z1l, wf2h, wf2l, bias2b,
                                          z2h, z2l, part);
    k_redstat<<<128, 256, 0, stream>>>(part, stats + ST2, E / 128);
    k_ec1_fin<<<BP * 64 / 256, 256, 0, stream>>>(z2h, z2l, stats + ST2, c1g2, c1e2,
                                                 x1, sq2);
    k_xsplit<<<BP * 64 / 256, 256, 0, stream>>>(x1, x1h, x1l);
    k_knn2<<<B * 32 * QC2, 128, 0, stream>>>(x1h, x1l, sq2, cand_d, cand_i);
    k_knn2m<<<BP / 256, 256, 0, stream>>>(cand_d, cand_i, idx2);
    k_ec2m<<<E / 128, 256, 0, stream>>>(x1h, x1l, idx2, wdh, wdl, w1h, w1l,
                                        c2b, zA, stats + ST3);
    k_ec2_fin<<<BP * 128 / 256, 256, 0, stream>>>(zA, stats + ST3, c2g, c2e, x2);
    k_xsplit<<<BP * 128 / 256, 256, 0, stream>>>(x2, x2h, x2l);
    k_l1m<<<256 * 8, 256, 0, stream>>>(x1h, x1l, x2h, x2l, wthL, wtlL, l1b,
                                       stats + ST4, pmax, pmin);
    k_pool<<<64, 256, 0, stream>>>(stats + ST4, l1g, l1e, pmax, pmin, pbuf);
    k_m1<<<32, 256, 0, stream>>>(pbuf, m1w, m1b, t1, stats + ST5);
    k_m2<<<16, 256, 0, stream>>>(t1, stats + ST5, m1g, m1e, m2w, m2b, t2, stats + ST6);
    k_m3<<<1, 256, 0, stream>>>(t2, stats + ST6, m2g, m2e, m3w, m3b, out);
}

// Round 18
// 628.983 us; speedup vs baseline: 1.0496x; 1.0108x over previous
//
#include <hip/hip_runtime.h>
#include <cmath>

constexpr int B = 16, P = 2048, KNN = 5;
constexpr int BP = B * P;           // 32768
constexpr int E = BP * KNN;         // 163840
constexpr float EPS = 1e-5f;
constexpr int QC2 = 2;              // q-chunks for knn2 (1024 blocks = 4/CU, longer scan streams)

// stats layout (floats): per stage [sum[C] | sumsq[C]]
constexpr int ST0 = 0;        // 64ch -> 128
constexpr int ST1 = 128;      // 64ch
constexpr int ST2 = 256;      // 64ch
constexpr int ST3 = 384;      // 128ch -> 256
constexpr int ST4 = 640;      // 1024ch -> 2048
constexpr int ST5 = 2688;     // 512ch -> 1024
constexpr int ST6 = 3712;     // 256ch -> 512
constexpr int ST_TOTAL = 4224;

typedef __attribute__((ext_vector_type(8))) short bf16x8;
typedef __attribute__((ext_vector_type(4))) float f32x4;

__device__ inline unsigned short f2bf(float x) {
    unsigned u = __float_as_uint(x);
    unsigned r = (u + 0x7FFFu + ((u >> 16) & 1u)) >> 16;
    return (unsigned short)r;
}
__device__ inline float bf2f(unsigned short h) {
    return __uint_as_float(((unsigned)h) << 16);
}
// split x into hi (bf16) and lo (bf16 of residual): x ~= hi + lo, err ~2^-18 rel
__device__ inline void split2bf(float x, unsigned short& h, unsigned short& l) {
    unsigned short hh = f2bf(x);
    h = hh;
    l = f2bf(x - bf2f(hh));
}

// branch-free sorted-5 insertion (ascending); constant indices -> stays in VGPRs.
__device__ inline void ins5(float d, int qi, float bd[KNN], int bi[KNN]) {
    bool c0 = d < bd[0], c1 = d < bd[1], c2 = d < bd[2], c3 = d < bd[3], c4 = d < bd[4];
    bd[4] = c3 ? bd[3] : (c4 ? d : bd[4]);  bi[4] = c3 ? bi[3] : (c4 ? qi : bi[4]);
    bd[3] = c2 ? bd[2] : (c3 ? d : bd[3]);  bi[3] = c2 ? bi[2] : (c3 ? qi : bi[3]);
    bd[2] = c1 ? bd[1] : (c2 ? d : bd[2]);  bi[2] = c1 ? bi[1] : (c2 ? qi : bi[2]);
    bd[1] = c0 ? bd[0] : (c1 ? d : bd[1]);  bi[1] = c0 ? bi[0] : (c1 ? qi : bi[1]);
    bd[0] = c0 ? d : bd[0];                 bi[0] = c0 ? qi : bi[0];
}
// insertion with lexicographic (d, qi) tie-break: keep lower q on exact fp tie
__device__ inline void ins5t(float d, int qi, float bd[KNN], int bi[KNN]) {
    bool c0 = (d < bd[0]) || (d == bd[0] && qi < bi[0]);
    bool c1 = (d < bd[1]) || (d == bd[1] && qi < bi[1]);
    bool c2 = (d < bd[2]) || (d == bd[2] && qi < bi[2]);
    bool c3 = (d < bd[3]) || (d == bd[3] && qi < bi[3]);
    bool c4 = (d < bd[4]) || (d == bd[4] && qi < bi[4]);
    bd[4] = c3 ? bd[3] : (c4 ? d : bd[4]);  bi[4] = c3 ? bi[3] : (c4 ? qi : bi[4]);
    bd[3] = c2 ? bd[2] : (c3 ? d : bd[3]);  bi[3] = c2 ? bi[2] : (c3 ? qi : bi[3]);
    bd[2] = c1 ? bd[1] : (c2 ? d : bd[2]);  bi[2] = c1 ? bi[1] : (c2 ? qi : bi[2]);
    bd[1] = c0 ? bd[0] : (c1 ? d : bd[1]);  bi[1] = c0 ? bi[0] : (c1 ? qi : bi[1]);
    bd[0] = c0 ? d : bd[0];                 bi[0] = c0 ? qi : bi[0];
}

// ---------------------------------------------------------------- init
__global__ void k_init(float* __restrict__ stats, float* __restrict__ pmax,
                       float* __restrict__ pmin) {
    int i = blockIdx.x * 256 + threadIdx.x;   // grid covers 16384
    if (i < ST_TOTAL) stats[i] = 0.f;
    if (i < B * 1024) { pmax[i] = 0.f; pmin[i] = INFINITY; }
}

// ---------------------------------------------------------------- deterministic partial reducer
__global__ __launch_bounds__(256) void k_redstat(const float* __restrict__ part,
        float* __restrict__ stats, int nblk) {
    __shared__ float r[256];
    int slot = blockIdx.x;
    float s = 0.f;
    for (int i = threadIdx.x; i < nblk; i += 256)
        s += part[(size_t)i * 128 + slot];
    r[threadIdx.x] = s; __syncthreads();
    for (int o = 128; o; o >>= 1) {
        if (threadIdx.x < o) r[threadIdx.x] += r[threadIdx.x + o];
        __syncthreads();
    }
    if (threadIdx.x == 0) stats[slot] = r[0];
}

// ---------------------------------------------------------------- weight pre-split: w[K][N] fp32 -> wt{h,l}[N][K] bf16
__global__ void k_wsplit(const float* __restrict__ w, unsigned short* __restrict__ th,
                         unsigned short* __restrict__ tl, int K, int N) {
    int i = blockIdx.x * 256 + threadIdx.x;
    if (i >= K * N) return;
    int k = i / N, n = i - k * N;          // read coalesced over n
    float f = w[i];
    unsigned short h = f2bf(f);
    th[(size_t)n * K + k] = h;
    tl[(size_t)n * K + k] = f2bf(f - bf2f(h));
}

// ---------------------------------------------------------------- BN-fold: wf[n][k] = scl[k]*w[k][n]; bias2 = bias + shf.w
__global__ __launch_bounds__(64) void k_wfold(const float* __restrict__ stats,
        const float* __restrict__ g, const float* __restrict__ be,
        const float* __restrict__ w, const float* __restrict__ bias,
        unsigned short* __restrict__ wfh, unsigned short* __restrict__ wfl,
        float* __restrict__ bias2, float invN) {
    __shared__ float red[64];
    int n = blockIdx.x, k = threadIdx.x;
    float mu = stats[k] * invN;
    float var = stats[64 + k] * invN - mu * mu;
    float sc = g[k] * rsqrtf(var + EPS);
    float sh = be[k] - mu * sc;
    float wv = w[k * 64 + n];
    float wf = sc * wv;
    unsigned short h, l;
    split2bf(wf, h, l);
    wfh[n * 64 + k] = h; wfl[n * 64 + k] = l;
    red[k] = sh * wv; __syncthreads();
    for (int o = 32; o; o >>= 1) {
        if (k < o) red[k] += red[k + o];
        __syncthreads();
    }
    if (k == 0) bias2[n] = bias[n] + red[0];
}

// ---------------------------------------------------------------- ec2 weight prep: W0-W1 and W1, transposed bf16 hi/lo
__global__ void k_wprep2(const float* __restrict__ w,   // c2w [128][128]
        unsigned short* __restrict__ wdh, unsigned short* __restrict__ wdl,
        unsigned short* __restrict__ w1h, unsigned short* __restrict__ w1l) {
    int i = blockIdx.x * 256 + threadIdx.x;  // 64*128
    if (i >= 64 * 128) return;
    int k = i >> 7, n = i & 127;
    float w0 = w[k * 128 + n];
    float w1 = w[(64 + k) * 128 + n];
    float wd = w0 - w1;
    unsigned short h, l;
    split2bf(wd, h, l); wdh[n * 64 + k] = h; wdl[n * 64 + k] = l;
    split2bf(w1, h, l); w1h[n * 64 + k] = h; w1l[n * 64 + k] = l;
}

// ---------------------------------------------------------------- x pre-split (same layout): fp32 [N] -> bf16 hi/lo
__global__ void k_xsplit(const float* __restrict__ x, unsigned short* __restrict__ xh,
                         unsigned short* __restrict__ xl) {
    int i = blockIdx.x * 256 + threadIdx.x;
    float f = x[i];
    unsigned short h, l;
    split2bf(f, h, l);
    xh[i] = h; xl[i] = l;
}

// ---------------------------------------------------------------- kNN on pos (D=3)
__global__ __launch_bounds__(256) void k_knn1(const float* __restrict__ pos,
                                              int* __restrict__ idx1) {
    __shared__ float4 qt[2048];   // all q staged once (32 KB)
    int b = blockIdx.x >> 5;
    int p0 = (blockIdx.x & 31) << 6;
    const float* posb = pos + (size_t)b * P * 3;
#pragma unroll
    for (int t = 0; t < 8; ++t) {
        int q = (t << 8) + threadIdx.x;
        float qx = posb[q * 3 + 0], qy = posb[q * 3 + 1], qz = posb[q * 3 + 2];
        qt[q] = make_float4(qx, qy, qz, qx * qx + qy * qy + qz * qz);
    }
    __syncthreads();
    int pl = threadIdx.x >> 2, sub = threadIdx.x & 3;
    int p = p0 + pl;
    float4 me = qt[p];
    float x = me.x, y = me.y, z = me.z, sqp = me.w;
    float bd[KNN]; int bi[KNN];
#pragma unroll
    for (int i = 0; i < KNN; ++i) { bd[i] = INFINITY; bi[i] = 0; }
    for (int j0 = 0; j0 < 512; j0 += 8) {
        float4 v[8];
#pragma unroll
        for (int u = 0; u < 8; ++u) v[u] = qt[((j0 + u) << 2) | sub];
#pragma unroll
        for (int u = 0; u < 8; ++u) {
            float dot = x * v[u].x + y * v[u].y + z * v[u].z;
            float d2 = sqp + v[u].w - 2.f * dot;
            if (d2 < bd[KNN - 1]) ins5(d2, ((j0 + u) << 2) | sub, bd, bi);
        }
    }
    // butterfly merge across the 4 subs; snapshot-then-insert
#pragma unroll
    for (int w = 1; w <= 2; w <<= 1) {
        float od[KNN]; int oi[KNN];
#pragma unroll
        for (int i = 0; i < KNN; ++i) {
            od[i] = __shfl_xor(bd[i], w, 64);
            oi[i] = __shfl_xor(bi[i], w, 64);
        }
#pragma unroll
        for (int i = 0; i < KNN; ++i) ins5t(od[i], oi[i], bd, bi);
    }
    if (sub == 0) {
        size_t o = ((size_t)b * P + p) * KNN;
#pragma unroll
        for (int i = 0; i < KNN; ++i) idx1[o + i] = bi[i];
    }
}

// ---------------------------------------------------------------- edgeconv1 layer0: e[6] @ w[6,64]; bf16 hi/lo out + partials
__global__ __launch_bounds__(256) void k_ec1_l0(const float* __restrict__ pos,
        const int* __restrict__ idx1, const float* __restrict__ w,
        const float* __restrict__ bias, unsigned short* __restrict__ zh,
        unsigned short* __restrict__ zl, float* __restrict__ part) {
    __shared__ float elds[256][6];
    __shared__ float red[256];
    int tid = threadIdx.x;
    int base = blockIdx.x * 256;
    {
        int e = base + tid;
        int bp = e / KNN;
        int bb = bp >> 11;
        int q = idx1[e];
        const float* pi = pos + (size_t)bp * 3;
        const float* pj = pos + ((size_t)(bb << 11) + q) * 3;
        float x0 = pi[0], x1v = pi[1], x2v = pi[2];
        elds[tid][0] = x0; elds[tid][1] = x1v; elds[tid][2] = x2v;
        elds[tid][3] = pj[0] - x0; elds[tid][4] = pj[1] - x1v; elds[tid][5] = pj[2] - x2v;
    }
    int c = tid & 63, lane = tid >> 6;
    float wr[6];
#pragma unroll
    for (int d = 0; d < 6; ++d) wr[d] = w[d * 64 + c];
    float bc = bias[c];
    __syncthreads();
    float s1 = 0.f, s2 = 0.f;
    for (int i = 0; i < 64; ++i) {
        int e = lane + (i << 2);
        float acc = bc;
#pragma unroll
        for (int d = 0; d < 6; ++d) acc = fmaf(elds[e][d], wr[d], acc);
        acc = fmaxf(acc, 0.f);
        unsigned short h, l;
        split2bf(acc, h, l);
        zh[(size_t)(base + e) * 64 + c] = h;
        zl[(size_t)(base + e) * 64 + c] = l;
        s1 += acc; s2 = fmaf(acc, acc, s2);
    }
    red[tid] = s1; __syncthreads();
    if (tid < 64) part[(size_t)blockIdx.x * 128 + tid] =
        red[tid] + red[tid + 64] + red[tid + 128] + red[tid + 192];
    __syncthreads();
    red[tid] = s2; __syncthreads();
    if (tid < 64) part[(size_t)blockIdx.x * 128 + 64 + tid] =
        red[tid] + red[tid + 64] + red[tid + 128] + red[tid + 192];
}

// ---------------------------------------------------------------- 64->64 layer (BN folded into weights; direct-frag MFMA)
__global__ __launch_bounds__(128) void k_lin64m(
        const unsigned short* __restrict__ zinh, const unsigned short* __restrict__ zinl,
        const unsigned short* __restrict__ wfh, const unsigned short* __restrict__ wfl,
        const float* __restrict__ bias2, unsigned short* __restrict__ zouth,
        unsigned short* __restrict__ zoutl, float* __restrict__ part) {
    __shared__ float red[2 * 64 * 2];
    int tid = threadIdx.x;
    int wv = tid >> 6, lane = tid & 63;
    int l15 = lane & 15, quad = lane >> 4;
    int row0 = blockIdx.x * 128 + wv * 64;
    f32x4 acc[4][4];
#pragma unroll
    for (int i = 0; i < 4; ++i)
#pragma unroll
        for (int j = 0; j < 4; ++j) acc[i][j] = (f32x4)0.f;

#pragma unroll
    for (int kc = 0; kc < 2; ++kc) {
        bf16x8 afh[4], afl[4], bfh[4], bfl[4];
#pragma unroll
        for (int i = 0; i < 4; ++i) {
            size_t o = (size_t)(row0 + i * 16 + l15) * 64 + kc * 32 + quad * 8;
            afh[i] = *(const bf16x8*)&zinh[o];
            afl[i] = *(const bf16x8*)&zinl[o];
        }
#pragma unroll
        for (int j = 0; j < 4; ++j) {
            size_t wo = (size_t)(j * 16 + l15) * 64 + kc * 32 + quad * 8;
            bfh[j] = *(const bf16x8*)&wfh[wo];
            bfl[j] = *(const bf16x8*)&wfl[wo];
        }
#pragma unroll
        for (int i = 0; i < 4; ++i)
#pragma unroll
            for (int j = 0; j < 4; ++j) {
                acc[i][j] = __builtin_amdgcn_mfma_f32_16x16x32_bf16(afh[i], bfh[j], acc[i][j], 0, 0, 0);
                acc[i][j] = __builtin_amdgcn_mfma_f32_16x16x32_bf16(afh[i], bfl[j], acc[i][j], 0, 0, 0);
                acc[i][j] = __builtin_amdgcn_mfma_f32_16x16x32_bf16(afl[i], bfh[j], acc[i][j], 0, 0, 0);
            }
    }
    // epilogue: bias + ReLU, bf16 split store, per-col stats
#pragma unroll
    for (int j = 0; j < 4; ++j) {
        int colL = j * 16 + l15;
        float bl = bias2[colL];
        float s1 = 0.f, s2 = 0.f;
#pragma unroll
        for (int i = 0; i < 4; ++i) {
            int row = row0 + i * 16 + quad * 4;
#pragma unroll
            for (int r = 0; r < 4; ++r) {
                float v = fmaxf(acc[i][j][r] + bl, 0.f);
                unsigned short h, l;
                split2bf(v, h, l);
                zouth[(size_t)(row + r) * 64 + colL] = h;
                zoutl[(size_t)(row + r) * 64 + colL] = l;
                s1 += v; s2 = fmaf(v, v, s2);
            }
        }
        s1 += __shfl_xor(s1, 16, 64); s1 += __shfl_xor(s1, 32, 64);
        s2 += __shfl_xor(s2, 16, 64); s2 += __shfl_xor(s2, 32, 64);
        if (quad == 0) {
            red[(wv * 64 + colL) * 2 + 0] = s1;
            red[(wv * 64 + colL) * 2 + 1] = s2;
        }
    }
    __syncthreads();
    if (tid < 64) {
        part[(size_t)blockIdx.x * 128 + tid] =
            red[tid * 2] + red[(64 + tid) * 2];
        part[(size_t)blockIdx.x * 128 + 64 + tid] =
            red[tid * 2 + 1] + red[(64 + tid) * 2 + 1];
    }
}

// ---------------------------------------------------------------- ec1 finalize: BN + max over k -> x1, sq norms (bf16 hi/lo in)
__global__ __launch_bounds__(256) void k_ec1_fin(const unsigned short* __restrict__ z2h,
        const unsigned short* __restrict__ z2l,
        const float* __restrict__ statsIn, const float* __restrict__ g,
        const float* __restrict__ be, float* __restrict__ x1,
        float* __restrict__ sq2) {
    int tid = threadIdx.x;
    int o = blockIdx.x * 256 + tid;
    int c = o & 63; int bp = o >> 6;
    float mu = statsIn[c] * (1.f / E);
    float var = statsIn[64 + c] * (1.f / E) - mu * mu;
    float sc = g[c] * rsqrtf(var + EPS);
    float sh = be[c] - mu * sc;
    float m = -INFINITY;
#pragma unroll
    for (int j = 0; j < KNN; ++j) {
        size_t zo = ((size_t)bp * KNN + j) * 64 + c;
        float v = bf2f(z2h[zo]) + bf2f(z2l[zo]);
        m = fmaxf(m, fmaf(v, sc, sh));
    }
    x1[o] = m;
    float ss = m * m;
#pragma unroll
    for (int off = 32; off; off >>= 1) ss += __shfl_down(ss, off, 64);
    if (c == 0) sq2[bp] = ss;
}

// ---------------------------------------------------------------- kNN2 partial (split-bf16 MFMA Gram + top-5 per q-chunk)
__global__ __launch_bounds__(128, 1) void k_knn2(const unsigned short* __restrict__ x1h,
        const unsigned short* __restrict__ x1l, const float* __restrict__ sq2,
        float* __restrict__ cd, int* __restrict__ ci) {
    __shared__ float S[2][32 * 129];   // per-wave key tile, stride 129 (bank rotate)
    int tid = threadIdx.x;
    int wv = tid >> 6, lane = tid & 63;
    int l15 = lane & 15, quad = lane >> 4;
    int qc = blockIdx.x & (QC2 - 1);
    int pt = blockIdx.x >> 1;                 // 16*32 ptiles of 64 rows
    int b = pt >> 5;
    int pw = ((pt & 31) << 6) + wv * 32;      // wave p base within batch
    const size_t xbase = (size_t)b * P * 64;
    float* Sw = &S[wv][0];

    // A fragments (rows pw..pw+31), kept for the whole kernel
    bf16x8 ah[2][2], al[2][2];
#pragma unroll
    for (int i = 0; i < 2; ++i)
#pragma unroll
        for (int kc = 0; kc < 2; ++kc) {
            size_t o = xbase + (size_t)(pw + i * 16 + l15) * 64 + kc * 32 + quad * 8;
            ah[i][kc] = *(const bf16x8*)&x1h[o];
            al[i][kc] = *(const bf16x8*)&x1l[o];
        }

    int half = lane >> 5;      // 0/1: which q-half this lane scans
    int pidx = lane & 31;      // which p row this lane scans
    float bd[KNN]; int bi[KNN];
#pragma unroll
    for (int i = 0; i < KNN; ++i) { bd[i] = INFINITY; bi[i] = 0; }

    int qlo = qc << 10;        // 1024-q chunk
    for (int t = 0; t < 8; ++t) {
        int q0 = qlo + (t << 7);
        float qsv[8];
#pragma unroll
        for (int j = 0; j < 8; ++j) qsv[j] = sq2[b * P + q0 + j * 16 + l15];
        f32x4 acc[2][8];
#pragma unroll
        for (int i = 0; i < 2; ++i)
#pragma unroll
            for (int j = 0; j < 8; ++j) acc[i][j] = (f32x4)0.f;
#pragma unroll
        for (int kc = 0; kc < 2; ++kc) {
            bf16x8 bh[8], bl[8];
#pragma unroll
            for (int j = 0; j < 8; ++j) {
                size_t o = xbase + (size_t)(q0 + j * 16 + l15) * 64 + kc * 32 + quad * 8;
                bh[j] = *(const bf16x8*)&x1h[o];
                bl[j] = *(const bf16x8*)&x1l[o];
            }
#pragma unroll
            for (int i = 0; i < 2; ++i)
#pragma unroll
                for (int j = 0; j < 8; ++j) {
                    acc[i][j] = __builtin_amdgcn_mfma_f32_16x16x32_bf16(ah[i][kc], bh[j], acc[i][j], 0, 0, 0);
                    acc[i][j] = __builtin_amdgcn_mfma_f32_16x16x32_bf16(ah[i][kc], bl[j], acc[i][j], 0, 0, 0);
                    acc[i][j] = __builtin_amdgcn_mfma_f32_16x16x32_bf16(al[i][kc], bh[j], acc[i][j], 0, 0, 0);
                }
        }
        // keys to LDS: S[p_local][q_local] = sq_q - 2*dot (sq_p dropped: row-constant)
#pragma unroll
        for (int i = 0; i < 2; ++i)
#pragma unroll
            for (int j = 0; j < 8; ++j)
#pragma unroll
                for (int r = 0; r < 4; ++r) {
                    int pl = i * 16 + quad * 4 + r;
                    Sw[pl * 129 + j * 16 + l15] = fmaf(acc[i][j][r], -2.f, qsv[j]);
                }
        // scan own rows (same wave wrote them; DS in-order -> no barrier)
        const float* row = Sw + pidx * 129 + half * 64;
        int qb = q0 + half * 64;
        for (int jj = 0; jj < 64; jj += 4) {
            float k0 = row[jj + 0], k1 = row[jj + 1], k2 = row[jj + 2], k3 = row[jj + 3];
            if (k0 < bd[4]) ins5(k0, qb + jj + 0, bd, bi);
            if (k1 < bd[4]) ins5(k1, qb + jj + 1, bd, bi);
            if (k2 < bd[4]) ins5(k2, qb + jj + 2, bd, bi);
            if (k3 < bd[4]) ins5(k3, qb + jj + 3, bd, bi);
        }
    }
    // merge the two half-lanes (one-directional: half==1's list stays immutable)
#pragma unroll
    for (int i = 0; i < KNN; ++i) {
        float od = __shfl_xor(bd[i], 32, 64);
        int oi = __shfl_xor(bi[i], 32, 64);
        if (half == 0) ins5t(od, oi, bd, bi);
    }
    if (half == 0) {
        size_t o = (((size_t)b * P + pw + pidx) * QC2 + qc) * KNN;
#pragma unroll
        for (int i = 0; i < KNN; ++i) { cd[o + i] = bd[i]; ci[o + i] = bi[i]; }
    }
}

// ---------------------------------------------------------------- kNN2 merge (QC2 sorted chunks of 5 -> 5)
__global__ __launch_bounds__(256) void k_knn2m(const float* __restrict__ cd,
        const int* __restrict__ ci, int* __restrict__ idx2) {
    int bp = blockIdx.x * 256 + threadIdx.x;
    float bd[KNN]; int bi[KNN];
#pragma unroll
    for (int i = 0; i < KNN; ++i) { bd[i] = INFINITY; bi[i] = 0; }
    size_t o = (size_t)bp * QC2 * KNN;
    for (int t = 0; t < QC2 * KNN; ++t) {
        float d2 = cd[o + t]; int qi = ci[o + t];
        if (d2 < bd[KNN - 1]) ins5(d2, qi, bd, bi);
    }
#pragma unroll
    for (int i = 0; i < KNN; ++i) idx2[bp * KNN + i] = bi[i];
}

// ---------------------------------------------------------------- edgeconv2 (direct-fragment split-bf16 MFMA)
__global__ __launch_bounds__(256) void k_ec2m(
        const unsigned short* __restrict__ x1h, const unsigned short* __restrict__ x1l,
        const int* __restrict__ idx2,
        const unsigned short* __restrict__ wdh, const unsigned short* __restrict__ wdl,
        const unsigned short* __restrict__ w1h, const unsigned short* __restrict__ w1l,
        const float* __restrict__ bias, float* __restrict__ zout,
        float* __restrict__ stats) {
    __shared__ float red[2 * 128 * 2];
    int tid = threadIdx.x;
    int base = blockIdx.x * 128;            // first edge
    int bb = base / (P * KNN);              // batch (blocks never straddle: 10240%128==0)
    int wv = tid >> 6, lane = tid & 63;
    int wm = wv >> 1, wn = wv & 1;
    int l15 = lane & 15, quad = lane >> 4;
    // per-lane A rows for this wave's 4 row-tiles
    int rI[4], rJ[4];
#pragma unroll
    for (int i = 0; i < 4; ++i) {
        int e = base + wm * 64 + i * 16 + l15;
        rI[i] = e / KNN;
        rJ[i] = (bb << 11) + idx2[e];
    }
    f32x4 acc[4][4];
#pragma unroll
    for (int i = 0; i < 4; ++i)
#pragma unroll
        for (int j = 0; j < 4; ++j) acc[i][j] = (f32x4)0.f;

#pragma unroll
    for (int s = 0; s < 2; ++s) {
        const unsigned short* bh_ = s ? w1h : wdh;
        const unsigned short* bl_ = s ? w1l : wdl;
#pragma unroll
        for (int kc = 0; kc < 2; ++kc) {
            bf16x8 afh[4], afl[4], bfh[4], bfl[4];
#pragma unroll
            for (int i = 0; i < 4; ++i) {
                int row = s ? rJ[i] : rI[i];
                size_t o = (size_t)row * 64 + kc * 32 + quad * 8;
                afh[i] = *(const bf16x8*)&x1h[o];
                afl[i] = *(const bf16x8*)&x1l[o];
            }
#pragma unroll
            for (int j = 0; j < 4; ++j) {
                size_t wo = (size_t)(wn * 64 + j * 16 + l15) * 64 + kc * 32 + quad * 8;
                bfh[j] = *(const bf16x8*)&bh_[wo];
                bfl[j] = *(const bf16x8*)&bl_[wo];
            }
#pragma unroll
            for (int i = 0; i < 4; ++i)
#pragma unroll
                for (int j = 0; j < 4; ++j) {
                    acc[i][j] = __builtin_amdgcn_mfma_f32_16x16x32_bf16(afh[i], bfh[j], acc[i][j], 0, 0, 0);
                    acc[i][j] = __builtin_amdgcn_mfma_f32_16x16x32_bf16(afh[i], bfl[j], acc[i][j], 0, 0, 0);
                    acc[i][j] = __builtin_amdgcn_mfma_f32_16x16x32_bf16(afl[i], bfh[j], acc[i][j], 0, 0, 0);
                }
        }
    }
    // epilogue: bias + ReLU, write z, per-col stats
#pragma unroll
    for (int j = 0; j < 4; ++j) {
        int colL = wn * 64 + j * 16 + l15;
        float bl = bias[colL];
        float s1 = 0.f, s2 = 0.f;
#pragma unroll
        for (int i = 0; i < 4; ++i) {
            int row = wm * 64 + i * 16 + quad * 4;
#pragma unroll
            for (int r = 0; r < 4; ++r) {
                float v = fmaxf(acc[i][j][r] + bl, 0.f);
                zout[(size_t)(base + row + r) * 128 + colL] = v;
                s1 += v; s2 = fmaf(v, v, s2);
            }
        }
        s1 += __shfl_xor(s1, 16, 64); s1 += __shfl_xor(s1, 32, 64);
        s2 += __shfl_xor(s2, 16, 64); s2 += __shfl_xor(s2, 32, 64);
        if (quad == 0) {
            red[(wm * 128 + colL) * 2 + 0] = s1;
            red[(wm * 128 + colL) * 2 + 1] = s2;
        }
    }
    __syncthreads();
    if (tid < 128) {
        atomicAdd(&stats[tid], red[tid * 2] + red[(128 + tid) * 2]);
        atomicAdd(&stats[128 + tid], red[tid * 2 + 1] + red[(128 + tid) * 2 + 1]);
    }
}

// ---------------------------------------------------------------- ec2 finalize: BN + max over k -> x2
__global__ __launch_bounds__(256) void k_ec2_fin(const float* __restrict__ z3,
        const float* __restrict__ stats, const float* __restrict__ g,
        const float* __restrict__ be, float* __restrict__ x2) {
    int o = blockIdx.x * 256 + threadIdx.x;
    int c = o & 127; int bp = o >> 7;
    float mu = stats[c] * (1.f / E);
    float var = stats[128 + c] * (1.f / E) - mu * mu;
    float sc = g[c] * rsqrtf(var + EPS);
    float sh = be[c] - mu * sc;
    float m = -INFINITY;
#pragma unroll
    for (int j = 0; j < KNN; ++j)
        m = fmaxf(m, fmaf(z3[((size_t)bp * KNN + j) * 128 + c], sc, sh));
    x2[o] = m;
}

// ---------------------------------------------------------------- l1 (direct-fragment split-bf16 MFMA, depth-2 pipelined)
// R17 counters: MfmaUtil 14.6%, VALUBusy 10% -> 75% idle = exposed L2 latency
// (16 dependent frag loads then 48 MFMAs per k-step at ~1.6 waves/SIMD).
// Fix: register double-buffer; issue step t+1's loads before step t's MFMAs.
__global__ __launch_bounds__(256) void k_l1m(
        const unsigned short* __restrict__ x1h, const unsigned short* __restrict__ x1l,
        const unsigned short* __restrict__ x2h, const unsigned short* __restrict__ x2l,
        const unsigned short* __restrict__ wth, const unsigned short* __restrict__ wtl,
        const float* __restrict__ bias, float* __restrict__ stats,
        float* __restrict__ pmax, float* __restrict__ pmin) {
    __shared__ float red[2 * 128 * 4];
    int tid = threadIdx.x;
    int brow = blockIdx.x & 255;
    int bcol = blockIdx.x >> 8;
    int row0 = brow << 7, col0 = bcol << 7;
    int wv = tid >> 6, lane = tid & 63;
    int wm = wv >> 1, wn = wv & 1;
    int l15 = lane & 15, quad = lane >> 4;
    f32x4 acc[4][4];
#pragma unroll
    for (int i = 0; i < 4; ++i)
#pragma unroll
        for (int j = 0; j < 4; ++j) acc[i][j] = (f32x4)0.f;

    auto loadA = [&](int k0, bf16x8* fh, bf16x8* fl) {
        const unsigned short* ah = (k0 < 64) ? x1h : x2h;
        const unsigned short* al = (k0 < 64) ? x1l : x2l;
        int astr = (k0 < 64) ? 64 : 128;
        int aoff = (k0 < 64) ? k0 : (k0 - 64);
#pragma unroll
        for (int i = 0; i < 4; ++i) {
            size_t o = (size_t)(row0 + wm * 64 + i * 16 + l15) * astr + aoff + quad * 8;
            fh[i] = *(const bf16x8*)&ah[o];
            fl[i] = *(const bf16x8*)&al[o];
        }
    };
    auto loadB = [&](int k0, bf16x8* fh, bf16x8* fl) {
#pragma unroll
        for (int j = 0; j < 4; ++j) {
            size_t wo = (size_t)(col0 + wn * 64 + j * 16 + l15) * 192 + k0 + quad * 8;
            fh[j] = *(const bf16x8*)&wth[wo];
            fl[j] = *(const bf16x8*)&wtl[wo];
        }
    };
    auto compute = [&](bf16x8* afh, bf16x8* afl, bf16x8* bfh, bf16x8* bfl) {
#pragma unroll
        for (int i = 0; i < 4; ++i)
#pragma unroll
            for (int j = 0; j < 4; ++j) {
                acc[i][j] = __builtin_amdgcn_mfma_f32_16x16x32_bf16(afh[i], bfh[j], acc[i][j], 0, 0, 0);
                acc[i][j] = __builtin_amdgcn_mfma_f32_16x16x32_bf16(afh[i], bfl[j], acc[i][j], 0, 0, 0);
                acc[i][j] = __builtin_amdgcn_mfma_f32_16x16x32_bf16(afl[i], bfh[j], acc[i][j], 0, 0, 0);
            }
    };

    bf16x8 A0h[4], A0l[4], B0h[4], B0l[4];
    bf16x8 A1h[4], A1l[4], B1h[4], B1l[4];
    loadA(0, A0h, A0l); loadB(0, B0h, B0l);
#pragma unroll
    for (int t = 0; t < 6; ++t) {
        if ((t & 1) == 0) {
            if (t < 5) { loadA((t + 1) * 32, A1h, A1l); loadB((t + 1) * 32, B1h, B1l); }
            compute(A0h, A0l, B0h, B0l);
        } else {
            if (t < 5) { loadA((t + 1) * 32, A0h, A0l); loadB((t + 1) * 32, B0h, B0l); }
            compute(A1h, A1l, B1h, B1l);
        }
    }
    // epilogue: bias + ReLU, per-col sum/sumsq/max/min (h never materialized)
#pragma unroll
    for (int j = 0; j < 4; ++j) {
        int colL = wn * 64 + j * 16 + l15;
        float bl = bias[col0 + colL];
        float s1 = 0.f, s2 = 0.f, mx = 0.f, mn = INFINITY;
#pragma unroll
        for (int i = 0; i < 4; ++i)
#pragma unroll
            for (int r = 0; r < 4; ++r) {
                float v = fmaxf(acc[i][j][r] + bl, 0.f);
                s1 += v; s2 = fmaf(v, v, s2);
                mx = fmaxf(mx, v); mn = fminf(mn, v);
            }
        s1 += __shfl_xor(s1, 16, 64); s1 += __shfl_xor(s1, 32, 64);
        s2 += __shfl_xor(s2, 16, 64); s2 += __shfl_xor(s2, 32, 64);
        mx = fmaxf(mx, __shfl_xor(mx, 16, 64)); mx = fmaxf(mx, __shfl_xor(mx, 32, 64));
        mn = fminf(mn, __shfl_xor(mn, 16, 64)); mn = fminf(mn, __shfl_xor(mn, 32, 64));
        if (quad == 0) {
            float* rp = &red[(wm * 128 + colL) * 4];
            rp[0] = s1; rp[1] = s2; rp[2] = mx; rp[3] = mn;
        }
    }
    __syncthreads();
    if (tid < 128) {
        const float* r0 = &red[tid * 4];
        const float* r1 = &red[(128 + tid) * 4];
        int bb = row0 >> 11;
        atomicAdd(&stats[col0 + tid], r0[0] + r1[0]);
        atomicAdd(&stats[1024 + col0 + tid], r0[1] + r1[1]);
        atomicMax((unsigned int*)&pmax[bb * 1024 + col0 + tid],
                  __float_as_uint(fmaxf(r0[2], r1[2])));
        atomicMin((unsigned int*)&pmin[bb * 1024 + col0 + tid],
                  __float_as_uint(fminf(r0[3], r1[3])));
    }
}

// ---------------------------------------------------------------- pooled p = BN(max or min)
__global__ void k_pool(const float* __restrict__ stats, const float* __restrict__ g,
                       const float* __restrict__ be, const float* __restrict__ pmax,
                       const float* __restrict__ pmin, float* __restrict__ p) {
    int o = blockIdx.x * 256 + threadIdx.x;   // 16384
    int c = o & 1023;
    float mu = stats[c] * (1.f / BP);
    float var = stats[1024 + c] * (1.f / BP) - mu * mu;
    float sc = g[c] * rsqrtf(var + EPS);
    float sh = be[c] - mu * sc;
    float v = (sc >= 0.f) ? pmax[o] : pmin[o];
    p[o] = fmaf(v, sc, sh);
}

// ---------------------------------------------------------------- head
__global__ __launch_bounds__(256) void k_m1(const float* __restrict__ p,
        const float* __restrict__ w, const float* __restrict__ bias,
        float* __restrict__ t1, float* __restrict__ stats) {
    int o = blockIdx.x * 256 + threadIdx.x;   // 8192
    int c = o & 511, b = o >> 9;
    const float* pr = p + (b << 10);
    float acc = bias[c];
    for (int k = 0; k < 1024; ++k) acc = fmaf(pr[k], w[k * 512 + c], acc);
    acc = fmaxf(acc, 0.f);
    t1[o] = acc;
    atomicAdd(&stats[c], acc);
    atomicAdd(&stats[512 + c], acc * acc);
}

__global__ __launch_bounds__(256) void k_m2(const float* __restrict__ t1,
        const float* __restrict__ stats5, const float* __restrict__ g,
        const float* __restrict__ be, const float* __restrict__ w,
        const float* __restrict__ bias, float* __restrict__ t2,
        float* __restrict__ stats6) {
    __shared__ float scl[512], shf[512];
    int tid = threadIdx.x;
    for (int t = tid; t < 512; t += 256) {
        float mu = stats5[t] * (1.f / 16.f);
        float var = stats5[512 + t] * (1.f / 16.f) - mu * mu;
        float sc = g[t] * rsqrtf(var + EPS);
        scl[t] = sc; shf[t] = be[t] - mu * sc;
    }
    __syncthreads();
    int o = blockIdx.x * 256 + tid;   // 4096
    int c = o & 255, b = o >> 8;
    const float* tr = t1 + (b << 9);
    float acc = bias[c];
    for (int k = 0; k < 512; ++k) {
        float u = fmaf(tr[k], scl[k], shf[k]);
        acc = fmaf(u, w[k * 256 + c], acc);
    }
    acc = fmaxf(acc, 0.f);
    t2[o] = acc;
    atomicAdd(&stats6[c], acc);
    atomicAdd(&stats6[256 + c], acc * acc);
}

__global__ __launch_bounds__(256) void k_m3(const float* __restrict__ t2,
        const float* __restrict__ stats6, const float* __restrict__ g,
        const float* __restrict__ be, const float* __restrict__ w,
        const float* __restrict__ bias, float* __restrict__ out) {
    __shared__ float scl[256], shf[256];
    int tid = threadIdx.x;
    {
        float mu = stats6[tid] * (1.f / 16.f);
        float var = stats6[256 + tid] * (1.f / 16.f) - mu * mu;
        float sc = g[tid] * rsqrtf(var + EPS);
        scl[tid] = sc; shf[tid] = be[tid] - mu * sc;
    }
    __syncthreads();
    if (tid < 32) {
        int c = tid & 1, b = tid >> 1;
        const float* tr = t2 + (b << 8);
        float acc = bias[c];
        for (int k = 0; k < 256; ++k) {
            float u = fmaf(tr[k], scl[k], shf[k]);
            acc = fmaf(u, w[k * 2 + c], acc);
        }
        out[tid] = acc;
    }
}

// ================================================================ launch
extern "C" void kernel_launch(void* const* d_in, const int* in_sizes, int n_in,
                              void* d_out, int out_size, void* d_ws, size_t ws_size,
                              hipStream_t stream) {
    const float* pos  = (const float*)d_in[0];
    const float* c1w0 = (const float*)d_in[1];
    const float* c1b0 = (const float*)d_in[2];
    const float* c1g0 = (const float*)d_in[3];
    const float* c1e0 = (const float*)d_in[4];
    const float* c1w1 = (const float*)d_in[5];
    const float* c1b1 = (const float*)d_in[6];
    const float* c1g1 = (const float*)d_in[7];
    const float* c1e1 = (const float*)d_in[8];
    const float* c1w2 = (const float*)d_in[9];
    const float* c1b2 = (const float*)d_in[10];
    const float* c1g2 = (const float*)d_in[11];
    const float* c1e2 = (const float*)d_in[12];
    const float* c2w  = (const float*)d_in[13];
    const float* c2b  = (const float*)d_in[14];
    const float* c2g  = (const float*)d_in[15];
    const float* c2e  = (const float*)d_in[16];
    const float* l1w  = (const float*)d_in[17];
    const float* l1b  = (const float*)d_in[18];
    const float* l1g  = (const float*)d_in[19];
    const float* l1e  = (const float*)d_in[20];
    const float* m1w  = (const float*)d_in[21];
    const float* m1b  = (const float*)d_in[22];
    const float* m1g  = (const float*)d_in[23];
    const float* m1e  = (const float*)d_in[24];
    const float* m2w  = (const float*)d_in[25];
    const float* m2b  = (const float*)d_in[26];
    const float* m2g  = (const float*)d_in[27];
    const float* m2e  = (const float*)d_in[28];
    const float* m3w  = (const float*)d_in[29];
    const float* m3b  = (const float*)d_in[30];
    float* out = (float*)d_out;

    char* ws = (char*)d_ws;
    size_t off = 0;
    auto alloc = [&](size_t bytes) {
        size_t r = off; off = (off + bytes + 255) & ~(size_t)255; return r;
    };
    float* stats = (float*)(ws + alloc(ST_TOTAL * 4));
    float* pmax  = (float*)(ws + alloc(16 * 1024 * 4));
    float* pmin  = (float*)(ws + alloc(16 * 1024 * 4));
    float* pbuf  = (float*)(ws + alloc(16 * 1024 * 4));
    float* t1    = (float*)(ws + alloc(16 * 512 * 4));
    float* t2    = (float*)(ws + alloc(16 * 256 * 4));
    float* sq2   = (float*)(ws + alloc((size_t)BP * 4));
    float* part  = (float*)(ws + alloc((size_t)(E / 64) * 128 * 4));  // up to 2560 blocks x 128
    unsigned short* wthL = (unsigned short*)(ws + alloc((size_t)192 * 1024 * 2));
    unsigned short* wtlL = (unsigned short*)(ws + alloc((size_t)192 * 1024 * 2));
    unsigned short* wdh  = (unsigned short*)(ws + alloc((size_t)128 * 64 * 2));
    unsigned short* wdl  = (unsigned short*)(ws + alloc((size_t)128 * 64 * 2));
    unsigned short* w1h  = (unsigned short*)(ws + alloc((size_t)128 * 64 * 2));
    unsigned short* w1l  = (unsigned short*)(ws + alloc((size_t)128 * 64 * 2));
    unsigned short* wf1h = (unsigned short*)(ws + alloc((size_t)64 * 64 * 2));
    unsigned short* wf1l = (unsigned short*)(ws + alloc((size_t)64 * 64 * 2));
    unsigned short* wf2h = (unsigned short*)(ws + alloc((size_t)64 * 64 * 2));
    unsigned short* wf2l = (unsigned short*)(ws + alloc((size_t)64 * 64 * 2));
    float* bias2a = (float*)(ws + alloc(64 * 4));
    float* bias2b = (float*)(ws + alloc(64 * 4));
    int*   idx1  = (int*)  (ws + alloc((size_t)E * 4));
    int*   idx2  = (int*)  (ws + alloc((size_t)E * 4));
    float* x1    = (float*)(ws + alloc((size_t)BP * 64 * 4));
    float* x2    = (float*)(ws + alloc((size_t)BP * 128 * 4));
    float* zA    = (float*)(ws + alloc((size_t)E * 128 * 4)); // hosts z0/z1 bf16 pairs, later z3 fp32
    float* zB    = (float*)(ws + alloc((size_t)E * 64 * 4));  // hosts z2 bf16 pair, later knn2 scratch
    // zA aliases: z0h/z0l (21MB each) then z1h/z1l; all dead before z3 (ec2 out) overwrites
    unsigned short* z0h = (unsigned short*)zA;
    unsigned short* z0l = z0h + (size_t)E * 64;
    unsigned short* z1h = z0l + (size_t)E * 64;
    unsigned short* z1l = z1h + (size_t)E * 64;
    // zB aliases: z2h/z2l (dead after ec1_fin), then knn2 scratch overwrites
    unsigned short* z2h = (unsigned short*)zB;
    unsigned short* z2l = z2h + (size_t)E * 64;
    unsigned short* x1h = (unsigned short*)zB;
    unsigned short* x1l = x1h + (size_t)BP * 64;
    float* cand_d = (float*)(x1l + (size_t)BP * 64);
    int*   cand_i = (int*)(cand_d + (size_t)BP * QC2 * KNN);
    unsigned short* x2h = (unsigned short*)(cand_i + (size_t)BP * QC2 * KNN);
    unsigned short* x2l = x2h + (size_t)BP * 128;

    (void)in_sizes; (void)n_in; (void)out_size; (void)ws_size;

    k_init<<<64, 256, 0, stream>>>(stats, pmax, pmin);
    k_wsplit<<<(192 * 1024 + 255) / 256, 256, 0, stream>>>(l1w, wthL, wtlL, 192, 1024);
    k_wprep2<<<(64 * 128 + 255) / 256, 256, 0, stream>>>(c2w, wdh, wdl, w1h, w1l);
    k_knn1<<<B * 32, 256, 0, stream>>>(pos, idx1);
    k_ec1_l0<<<E / 256, 256, 0, stream>>>(pos, idx1, c1w0, c1b0, z0h, z0l, part);
    k_redstat<<<128, 256, 0, stream>>>(part, stats + ST0, E / 256);
    k_wfold<<<64, 64, 0, stream>>>(stats + ST0, c1g0, c1e0, c1w1, c1b1,
                                   wf1h, wf1l, bias2a, 1.f / E);
    k_lin64m<<<E / 128, 128, 0, stream>>>(z0h, z0l, wf1h, wf1l, bias2a,
                                          z1h, z1l, part);
    k_redstat<<<128, 256, 0, stream>>>(part, stats + ST1, E / 128);
    k_wfold<<<64, 64, 0, stream>>>(stats + ST1, c1g1, c1e1, c1w2, c1b2,
                                   wf2h, wf2l, bias2b, 1.f / E);
    k_lin64m<<<E / 128, 128, 0, stream>>>(z1h, z1l, wf2h, wf2l, bias2b,
                                          z2h, z2l, part);
    k_redstat<<<128, 256, 0, stream>>>(part, stats + ST2, E / 128);
    k_ec1_fin<<<BP * 64 / 256, 256, 0, stream>>>(z2h, z2l, stats + ST2, c1g2, c1e2,
                                                 x1, sq2);
    k_xsplit<<<BP * 64 / 256, 256, 0, stream>>>(x1, x1h, x1l);
    k_knn2<<<B * 32 * QC2, 128, 0, stream>>>(x1h, x1l, sq2, cand_d, cand_i);
    k_knn2m<<<BP / 256, 256, 0, stream>>>(cand_d, cand_i, idx2);
    k_ec2m<<<E / 128, 256, 0, stream>>>(x1h, x1l, idx2, wdh, wdl, w1h, w1l,
                                        c2b, zA, stats + ST3);
    k_ec2_fin<<<BP * 128 / 256, 256, 0, stream>>>(zA, stats + ST3, c2g, c2e, x2);
    k_xsplit<<<BP * 128 / 256, 256, 0, stream>>>(x2, x2h, x2l);
    k_l1m<<<256 * 8, 256, 0, stream>>>(x1h, x1l, x2h, x2l, wthL, wtlL, l1b,
                                       stats + ST4, pmax, pmin);
    k_pool<<<64, 256, 0, stream>>>(stats + ST4, l1g, l1e, pmax, pmin, pbuf);
    k_m1<<<32, 256, 0, stream>>>(pbuf, m1w, m1b, t1, stats + ST5);
    k_m2<<<16, 256, 0, stream>>>(t1, stats + ST5, m1g, m1e, m2w, m2b, t2, stats + ST6);
    k_m3<<<1, 256, 0, stream>>>(t2, stats + ST6, m2g, m2e, m3w, m3b, out);
}